// Round 1
// 2368.872 us; speedup vs baseline: 1.2561x; 1.2561x over previous
//
#include <hip/hip_runtime.h>
#include <math.h>

// Problem constants
#define B_ 32
#define T_ 2048
#define D_ 256
#define H_ 512
#define O_ 256
#define S_CH 8               // chunk length (was 32): 4x fewer serial steps
#define C_CH 256             // number of chunks = T/S: 1 block per CU

typedef short bf16x8 __attribute__((ext_vector_type(8)));  // 8 bf16 (4 VGPRs) MFMA frag
typedef float f32x4  __attribute__((ext_vector_type(4)));

__device__ __forceinline__ unsigned short f2bf_rne(float x) {
    unsigned int u = __builtin_bit_cast(unsigned int, x);
    unsigned int r = (u + 0x7fffu + ((u >> 16) & 1u)) >> 16;
    return (unsigned short)r;
}
__device__ __forceinline__ float bf2f(unsigned short h) {
    unsigned int u = ((unsigned int)h) << 16;
    return __builtin_bit_cast(float, u);
}

#define MFMA16(a, b, c) __builtin_amdgcn_mfma_f32_16x16x32_bf16((a), (b), (c), 0, 0, 0)

// Build split-bf16 A-fragments (hi+lo) from 8 consecutive fp32 values.
__device__ __forceinline__ void split_frag(const float* p, bf16x8& hi, bf16x8& lo) {
    f32x4 a = *(const f32x4*)p;
    f32x4 b = *(const f32x4*)(p + 4);
#pragma unroll
    for (int i = 0; i < 4; i++) {
        unsigned short h = f2bf_rne(a[i]);
        hi[i] = (short)h; lo[i] = (short)f2bf_rne(a[i] - bf2f(h));
        unsigned short h2 = f2bf_rne(b[i]);
        hi[4 + i] = (short)h2; lo[4 + i] = (short)f2bf_rne(b[i] - bf2f(h2));
    }
}

// Fragment-major packed offset for a B-matrix element (n, k), KB = K/32.
__device__ __forceinline__ size_t wpack_off(int n, int k, int KB) {
    int n16 = n >> 4, l15 = n & 15;
    int kb = k >> 5, lhi = (k >> 3) & 3, j = k & 7;
    return (((size_t)(n16 * KB + kb) * 4 + lhi) * 16 + l15) * 8 + j;
}

// Same layout for the LDS-resident h state (m over 32 batches, n over 512).
__device__ __forceinline__ int hfrag_off(int m, int n) {
    int m16 = m >> 4, l15m = m & 15;
    int kb = n >> 5, lhi = (n >> 3) & 3, j = n & 7;
    return (((m16 * 16 + kb) * 4 + lhi) * 16 + l15m) * 8 + j;
}

// ---------------------------------------------------------------------------
// Pack fp32 matrix into frag-major bf16 hi/lo. kshift: 9 (K=512) or 8 (K=256).
// ---------------------------------------------------------------------------
__global__ void k_pack(const float* __restrict__ in, unsigned short* __restrict__ hi,
                       unsigned short* __restrict__ lo, int total, int kshift) {
    int i = blockIdx.x * 256 + threadIdx.x;
    if (i < total) {
        int n = i >> kshift;
        int k = i & ((1 << kshift) - 1);
        float v = in[i];
        unsigned short h = f2bf_rne(v);
        size_t o = wpack_off(n, k, 1 << (kshift - 5));
        hi[o] = h;
        lo[o] = f2bf_rne(v - bf2f(h));
    }
}

// ---------------------------------------------------------------------------
// fp32 matrix square: Out = In * In  (512x512), grid (16,16), block 256
// ---------------------------------------------------------------------------
__global__ __launch_bounds__(256) void k_sq(const float* __restrict__ In, float* __restrict__ Out) {
    __shared__ float As[32][33];
    __shared__ float Bs[32][33];
    int tx = threadIdx.x & 15, ty = threadIdx.x >> 4;
    int j0 = blockIdx.x * 32, i0 = blockIdx.y * 32;
    float a00 = 0.f, a01 = 0.f, a10 = 0.f, a11 = 0.f;
    int r  = threadIdx.x >> 3;
    int c4 = (threadIdx.x & 7) * 4;
    for (int kb = 0; kb < H_ / 32; kb++) {
        f32x4 va = *(const f32x4*)(In + (size_t)(i0 + r) * H_ + kb * 32 + c4);
        f32x4 vb = *(const f32x4*)(In + (size_t)(kb * 32 + r) * H_ + j0 + c4);
        __syncthreads();
        As[r][c4 + 0] = va[0]; As[r][c4 + 1] = va[1]; As[r][c4 + 2] = va[2]; As[r][c4 + 3] = va[3];
        Bs[r][c4 + 0] = vb[0]; Bs[r][c4 + 1] = vb[1]; Bs[r][c4 + 2] = vb[2]; Bs[r][c4 + 3] = vb[3];
        __syncthreads();
#pragma unroll
        for (int k = 0; k < 32; k++) {
            float b0 = Bs[k][tx * 2], b1 = Bs[k][tx * 2 + 1];
            float a0 = As[ty * 2][k], a1 = As[ty * 2 + 1][k];
            a00 += a0 * b0; a01 += a0 * b1; a10 += a1 * b0; a11 += a1 * b1;
        }
    }
    Out[(size_t)(i0 + ty * 2) * H_ + j0 + tx * 2]     = a00;
    Out[(size_t)(i0 + ty * 2) * H_ + j0 + tx * 2 + 1] = a01;
    Out[(size_t)(i0 + ty * 2 + 1) * H_ + j0 + tx * 2]     = a10;
    Out[(size_t)(i0 + ty * 2 + 1) * H_ + j0 + tx * 2 + 1] = a11;
}

// ---------------------------------------------------------------------------
// Seed the chunk-carry scan inputs: v[0]=h0, v[c]=l_end(c-1) from zb.
// ---------------------------------------------------------------------------
__global__ void k_seed(const float* __restrict__ h0, const float* __restrict__ zb,
                       float* __restrict__ Va) {
    int i = blockIdx.x * 256 + threadIdx.x;  // over C*B*H
    int c = i >> 14;             // B*H = 16384
    int bn = i & 16383;
    int b = bn >> 9, n = bn & 511;
    Va[i] = (c == 0) ? h0[bn] : zb[((size_t)b * T_ + (c * S_CH - 1)) * H_ + n];
}

// ---------------------------------------------------------------------------
// One Kogge-Stone scan level: Vout[c] = Vin[c] + W^(S*s) . Vin[c-s]  (c >= s),
// else copy. fp32. W is row-major [n][k]; staged transposed through LDS.
// grid (16, C_CH): x = n-tile, y = c. block 256.
// ---------------------------------------------------------------------------
__global__ __launch_bounds__(256) void k_scan(const float* __restrict__ Vin,
                                              const float* __restrict__ W,
                                              float* __restrict__ Vout, int s) {
    int c  = blockIdx.y;
    int j0 = blockIdx.x * 32;
    int r  = threadIdx.x >> 3;
    int c4 = (threadIdx.x & 7) * 4;
    size_t rowout = ((size_t)c * B_ + r) * H_ + j0 + c4;
    if (c < s) {
        *(f32x4*)(Vout + rowout) = *(const f32x4*)(Vin + rowout);
        return;
    }
    __shared__ float As[32][33];
    __shared__ float Bs[32][33];
    int tx = threadIdx.x & 15, ty = threadIdx.x >> 4;
    float a00 = 0.f, a01 = 0.f, a10 = 0.f, a11 = 0.f;
    size_t base_in = ((size_t)(c - s) * B_) * H_;
    for (int kb = 0; kb < H_ / 32; kb++) {
        f32x4 va = *(const f32x4*)(Vin + base_in + (size_t)r * H_ + kb * 32 + c4);
        f32x4 vb = *(const f32x4*)(W + (size_t)(j0 + r) * H_ + kb * 32 + c4);  // W rows j0..j0+31
        __syncthreads();
        As[r][c4 + 0] = va[0]; As[r][c4 + 1] = va[1]; As[r][c4 + 2] = va[2]; As[r][c4 + 3] = va[3];
        Bs[c4 + 0][r] = vb[0]; Bs[c4 + 1][r] = vb[1]; Bs[c4 + 2][r] = vb[2]; Bs[c4 + 3][r] = vb[3];
        __syncthreads();
#pragma unroll
        for (int k = 0; k < 32; k++) {
            float b0 = Bs[k][tx * 2], b1 = Bs[k][tx * 2 + 1];
            float a0 = As[ty * 2][k], a1 = As[ty * 2 + 1][k];
            a00 += a0 * b0; a01 += a0 * b1; a10 += a1 * b0; a11 += a1 * b1;
        }
    }
    size_t o = ((size_t)c * B_) * H_;
    int m0 = ty * 2, n0 = j0 + tx * 2;
    Vout[o + (size_t)m0 * H_ + n0]           = a00 + Vin[o + (size_t)m0 * H_ + n0];
    Vout[o + (size_t)m0 * H_ + n0 + 1]       = a01 + Vin[o + (size_t)m0 * H_ + n0 + 1];
    Vout[o + (size_t)(m0 + 1) * H_ + n0]     = a10 + Vin[o + (size_t)(m0 + 1) * H_ + n0];
    Vout[o + (size_t)(m0 + 1) * H_ + n0 + 1] = a11 + Vin[o + (size_t)(m0 + 1) * H_ + n0 + 1];
}

// ---------------------------------------------------------------------------
// K0: zb[b][t][h] = x[b][t][:] @ W_ih^T + (b_ih + b_hh), fp32, into the z
// region of d_out. x split hi/lo on the fly; W_ih pre-split+packed; 3 MFMAs.
// grid (T/64, B), block 512 (8 waves; wave w owns n-slice 64w..64w+63)
// ---------------------------------------------------------------------------
__global__ __launch_bounds__(512) void k_xw(const float* __restrict__ x,
                                            const unsigned short* __restrict__ Wp_hi,
                                            const unsigned short* __restrict__ Wp_lo,
                                            const float* __restrict__ bih,
                                            const float* __restrict__ bhh,
                                            float* __restrict__ zb) {
    int b  = blockIdx.y;
    int t0 = blockIdx.x * 64;
    int w    = threadIdx.x >> 6;
    int lane = threadIdx.x & 63;
    int l15 = lane & 15, lhi = lane >> 4;
    int nb = w * 64;

    f32x4 acc[4][4];  // [mt][nt]
    for (int mt = 0; mt < 4; mt++)
        for (int nt = 0; nt < 4; nt++)
            acc[mt][nt] = (f32x4){0.f, 0.f, 0.f, 0.f};

    const float* xb = x + (size_t)b * T_ * D_;
    for (int kb = 0; kb < D_ / 32; kb++) {
        int kofs = kb * 32 + lhi * 8;
        bf16x8 ah[4], al[4];
#pragma unroll
        for (int mt = 0; mt < 4; mt++) {
            int t = t0 + mt * 16 + l15;
            split_frag(xb + (size_t)t * D_ + kofs, ah[mt], al[mt]);
        }
#pragma unroll
        for (int nt = 0; nt < 4; nt++) {
            size_t wb = (((size_t)(w * 4 + nt) * 8 + kb) << 9) + lane * 8;  // KB=8
            bf16x8 bh = *(const bf16x8*)(Wp_hi + wb);
            bf16x8 bl = *(const bf16x8*)(Wp_lo + wb);
#pragma unroll
            for (int mt = 0; mt < 4; mt++) {
                acc[mt][nt] = MFMA16(ah[mt], bh, acc[mt][nt]);
                acc[mt][nt] = MFMA16(al[mt], bh, acc[mt][nt]);
                acc[mt][nt] = MFMA16(ah[mt], bl, acc[mt][nt]);
            }
        }
    }
#pragma unroll
    for (int nt = 0; nt < 4; nt++) {
        int n = nb + nt * 16 + l15;
        float bias = bih[n] + bhh[n];
#pragma unroll
        for (int mt = 0; mt < 4; mt++) {
#pragma unroll
            for (int r = 0; r < 4; r++) {
                int t = t0 + mt * 16 + lhi * 4 + r;
                zb[((size_t)b * T_ + t) * H_ + n] = acc[mt][nt][r] + bias;
            }
        }
    }
}

// ---------------------------------------------------------------------------
// Phase 1: per-chunk local recurrence l_t = xw_t + l_{t-1} @ W_hh^T (from 0),
// in place over zb (fp32, [b][t][h]). State fp32 via split-bf16 hi/lo LDS in
// frag-major layout; packed Whh -> coalesced B loads. grid C_CH, block 512.
// ---------------------------------------------------------------------------
__global__ __launch_bounds__(512) void k_phase1(const unsigned short* __restrict__ Wp_hi,
                                                const unsigned short* __restrict__ Wp_lo,
                                                float* __restrict__ zb) {
    __shared__ __attribute__((aligned(16))) unsigned short hA[16384];
    __shared__ __attribute__((aligned(16))) unsigned short lA[16384];
    int c = blockIdx.x;
    int w = threadIdx.x >> 6;
    int lane = threadIdx.x & 63;
    int l15 = lane & 15, lhi = lane >> 4;

    for (int i = threadIdx.x; i < 16384; i += 512) { hA[i] = 0; lA[i] = 0; }
    __syncthreads();

    for (int j = 0; j < S_CH; j++) {
        int t = c * S_CH + j;
        f32x4 acc[2][4];
#pragma unroll
        for (int mt = 0; mt < 2; mt++) {
#pragma unroll
            for (int nt = 0; nt < 4; nt++) {
                int n = w * 64 + nt * 16 + l15;
#pragma unroll
                for (int r = 0; r < 4; r++) {
                    int b = mt * 16 + lhi * 4 + r;
                    acc[mt][nt][r] = zb[((size_t)b * T_ + t) * H_ + n];
                }
            }
        }
        if (j > 0) {
            for (int kb = 0; kb < 16; kb++) {
                bf16x8 ah0 = *(const bf16x8*)&hA[(kb << 9) + lane * 8];
                bf16x8 ah1 = *(const bf16x8*)&hA[((16 + kb) << 9) + lane * 8];
                bf16x8 al0 = *(const bf16x8*)&lA[(kb << 9) + lane * 8];
                bf16x8 al1 = *(const bf16x8*)&lA[((16 + kb) << 9) + lane * 8];
#pragma unroll
                for (int nt = 0; nt < 4; nt++) {
                    size_t wb = (((size_t)(w * 4 + nt) * 16 + kb) << 9) + lane * 8;
                    bf16x8 bh = *(const bf16x8*)(Wp_hi + wb);
                    bf16x8 bl = *(const bf16x8*)(Wp_lo + wb);
                    acc[0][nt] = MFMA16(ah0, bh, acc[0][nt]);
                    acc[0][nt] = MFMA16(al0, bh, acc[0][nt]);
                    acc[0][nt] = MFMA16(ah0, bl, acc[0][nt]);
                    acc[1][nt] = MFMA16(ah1, bh, acc[1][nt]);
                    acc[1][nt] = MFMA16(al1, bh, acc[1][nt]);
                    acc[1][nt] = MFMA16(ah1, bl, acc[1][nt]);
                }
            }
        }
        __syncthreads();  // all waves done reading previous h before overwrite
#pragma unroll
        for (int mt = 0; mt < 2; mt++) {
#pragma unroll
            for (int nt = 0; nt < 4; nt++) {
                int n = w * 64 + nt * 16 + l15;
#pragma unroll
                for (int r = 0; r < 4; r++) {
                    int b = mt * 16 + lhi * 4 + r;
                    float v = acc[mt][nt][r];
                    zb[((size_t)b * T_ + t) * H_ + n] = v;  // l_t (fp32)
                    unsigned short hi = f2bf_rne(v);
                    int o = hfrag_off(b, n);
                    hA[o] = hi;
                    lA[o] = f2bf_rne(v - bf2f(hi));
                }
            }
        }
        __syncthreads();
    }
}

// ---------------------------------------------------------------------------
// Phase 3: z_t = l_t + W^{j+1}.Hin[c], v <- W.v per step (split-bf16 MFMA).
// Reads l_t (fp32) from zb and overwrites with final z_t (fp32) in place.
// grid C_CH, block 512.
// ---------------------------------------------------------------------------
__global__ __launch_bounds__(512) void k_phase3(const unsigned short* __restrict__ Wp_hi,
                                                const unsigned short* __restrict__ Wp_lo,
                                                const float* __restrict__ Hin,
                                                float* __restrict__ zb) {
    __shared__ __attribute__((aligned(16))) unsigned short hA[16384];
    __shared__ __attribute__((aligned(16))) unsigned short lA[16384];
    int c = blockIdx.x;
    int w = threadIdx.x >> 6;
    int lane = threadIdx.x & 63;
    int l15 = lane & 15, lhi = lane >> 4;

    for (int i = threadIdx.x; i < 16384; i += 512) {
        int m = i >> 9, n = i & 511;
        float v = Hin[((size_t)c * B_ + m) * H_ + n];
        unsigned short hi = f2bf_rne(v);
        int o = hfrag_off(m, n);
        hA[o] = hi;
        lA[o] = f2bf_rne(v - bf2f(hi));
    }
    __syncthreads();

    for (int j = 0; j < S_CH; j++) {
        int t = c * S_CH + j;
        f32x4 acc[2][4];
#pragma unroll
        for (int mt = 0; mt < 2; mt++)
#pragma unroll
            for (int nt = 0; nt < 4; nt++) acc[mt][nt] = (f32x4){0.f, 0.f, 0.f, 0.f};
        for (int kb = 0; kb < 16; kb++) {
            bf16x8 ah0 = *(const bf16x8*)&hA[(kb << 9) + lane * 8];
            bf16x8 ah1 = *(const bf16x8*)&hA[((16 + kb) << 9) + lane * 8];
            bf16x8 al0 = *(const bf16x8*)&lA[(kb << 9) + lane * 8];
            bf16x8 al1 = *(const bf16x8*)&lA[((16 + kb) << 9) + lane * 8];
#pragma unroll
            for (int nt = 0; nt < 4; nt++) {
                size_t wb = (((size_t)(w * 4 + nt) * 16 + kb) << 9) + lane * 8;
                bf16x8 bh = *(const bf16x8*)(Wp_hi + wb);
                bf16x8 bl = *(const bf16x8*)(Wp_lo + wb);
                acc[0][nt] = MFMA16(ah0, bh, acc[0][nt]);
                acc[0][nt] = MFMA16(al0, bh, acc[0][nt]);
                acc[0][nt] = MFMA16(ah0, bl, acc[0][nt]);
                acc[1][nt] = MFMA16(ah1, bh, acc[1][nt]);
                acc[1][nt] = MFMA16(al1, bh, acc[1][nt]);
                acc[1][nt] = MFMA16(ah1, bl, acc[1][nt]);
            }
        }
        __syncthreads();
#pragma unroll
        for (int mt = 0; mt < 2; mt++) {
#pragma unroll
            for (int nt = 0; nt < 4; nt++) {
                int n = w * 64 + nt * 16 + l15;
#pragma unroll
                for (int r = 0; r < 4; r++) {
                    int b = mt * 16 + lhi * 4 + r;
                    float vv = acc[mt][nt][r];
                    size_t zi = ((size_t)b * T_ + t) * H_ + n;
                    zb[zi] = vv + zb[zi];            // final z_t = l_t + W^{j+1} h_in
                    unsigned short hi = f2bf_rne(vv);
                    int o = hfrag_off(b, n);
                    hA[o] = hi;
                    lA[o] = f2bf_rne(vv - bf2f(hi));
                }
            }
        }
        __syncthreads();
    }
}

// ---------------------------------------------------------------------------
// K5: logits = z @ W_lin^T + b_lin, fused softmax over O=256, fp32 out.
// grid (B*T/64), block 256 (4 waves; wave w owns rows 16w..16w+15, all cols).
// ---------------------------------------------------------------------------
__global__ __launch_bounds__(256) void k_logits(const float* __restrict__ zq,
                                                const unsigned short* __restrict__ Wp_hi,
                                                const float* __restrict__ blin,
                                                float* __restrict__ out) {
    size_t row0 = (size_t)blockIdx.x * 64;
    int w = threadIdx.x >> 6, lane = threadIdx.x & 63;
    int l15 = lane & 15, lhi = lane >> 4;

    f32x4 acc[16];
#pragma unroll
    for (int nt = 0; nt < 16; nt++) acc[nt] = (f32x4){0.f, 0.f, 0.f, 0.f};

    const float* arow = zq + (row0 + (size_t)w * 16 + l15) * H_;
    for (int kb = 0; kb < 16; kb++) {
        int kofs = kb * 32 + lhi * 8;
        bf16x8 ah, al;
        split_frag(arow + kofs, ah, al);
#pragma unroll
        for (int nt = 0; nt < 16; nt++) {
            size_t wb = (((size_t)nt * 16 + kb) << 9) + lane * 8;  // n16 = nt, KB=16
            bf16x8 bh = *(const bf16x8*)(Wp_hi + wb);
            acc[nt] = MFMA16(ah, bh, acc[nt]);
            acc[nt] = MFMA16(al, bh, acc[nt]);
        }
    }
#pragma unroll
    for (int nt = 0; nt < 16; nt++) {
        float bb = blin[nt * 16 + l15];
#pragma unroll
        for (int r = 0; r < 4; r++) acc[nt][r] += bb;
    }
    float rmax[4], rinv[4];
#pragma unroll
    for (int r = 0; r < 4; r++) {
        float mx = -INFINITY;
#pragma unroll
        for (int nt = 0; nt < 16; nt++) mx = fmaxf(mx, acc[nt][r]);
        for (int s = 1; s < 16; s <<= 1) mx = fmaxf(mx, __shfl_xor(mx, s));
        float sum = 0.f;
#pragma unroll
        for (int nt = 0; nt < 16; nt++) sum += __expf(acc[nt][r] - mx);
        for (int s = 1; s < 16; s <<= 1) sum += __shfl_xor(sum, s);
        rmax[r] = mx;
        rinv[r] = 1.f / sum;
    }
#pragma unroll
    for (int nt = 0; nt < 16; nt++) {
#pragma unroll
        for (int r = 0; r < 4; r++) {
            float e = __expf(acc[nt][r] - rmax[r]) * rinv[r];
            size_t row = row0 + (size_t)w * 16 + lhi * 4 + r;
            out[row * O_ + nt * 16 + l15] = e;
        }
    }
}

// ---------------------------------------------------------------------------
extern "C" void kernel_launch(void* const* d_in, const int* in_sizes, int n_in,
                              void* d_out, int out_size, void* d_ws, size_t ws_size,
                              hipStream_t stream) {
    const float* x    = (const float*)d_in[0];
    const float* h0   = (const float*)d_in[1];
    const float* Wih  = (const float*)d_in[2];
    const float* Whh  = (const float*)d_in[3];
    const float* bih  = (const float*)d_in[4];
    const float* bhh  = (const float*)d_in[5];
    const float* Wlin = (const float*)d_in[6];
    const float* blin = (const float*)d_in[7];

    float* out  = (float*)d_out;
    float* zout = out + (size_t)B_ * T_ * O_;  // z region of d_out (fp32, in-place scan)

    // ws layout: Q[0..9] (W^2..W^1024) | packed bf16 splits. ~12.6 MB.
    // Va/Vb (16 MB each) live in the softmax-out region of d_out, which is
    // dead until k_logits (the final launch).
    float* ws = (float*)d_ws;
    float* Q[10];
    for (int i = 0; i < 10; i++) Q[i] = ws + (size_t)i * H_ * H_;
    unsigned short* Whh_hi = (unsigned short*)(ws + (size_t)10 * H_ * H_);
    unsigned short* Whh_lo = Whh_hi + (size_t)H_ * H_;
    unsigned short* Wih_hi = Whh_lo + (size_t)H_ * H_;
    unsigned short* Wih_lo = Wih_hi + (size_t)H_ * D_;
    unsigned short* Wlin_hi = Wih_lo + (size_t)H_ * D_;
    unsigned short* Wlin_lo = Wlin_hi + (size_t)O_ * H_;
    (void)Wlin_lo;

    float* Va = out;                            // 16 MB, dead until k_logits
    float* Vb = out + (size_t)C_CH * B_ * H_;   // 16 MB, ends at 32 MB < 64 MB

    // Pack weights (frag-major, bf16 hi/lo)
    k_pack<<<dim3((H_ * H_) / 256), 256, 0, stream>>>(Whh, Whh_hi, Whh_lo, H_ * H_, 9);
    k_pack<<<dim3((H_ * D_) / 256), 256, 0, stream>>>(Wih, Wih_hi, Wih_lo, H_ * D_, 8);
    k_pack<<<dim3((O_ * H_) / 256), 256, 0, stream>>>(Wlin, Wlin_hi, Wlin_lo, O_ * H_, 9);

    // Squaring chain: Q[i] = W^(2^(i+1)), i=0..9  (W^2 .. W^1024)
    k_sq<<<dim3(16, 16), 256, 0, stream>>>(Whh, Q[0]);
    for (int i = 1; i < 10; i++)
        k_sq<<<dim3(16, 16), 256, 0, stream>>>(Q[i - 1], Q[i]);

    // xw into z region
    k_xw<<<dim3(T_ / 64, B_), 512, 0, stream>>>(x, Wih_hi, Wih_lo, bih, bhh, zout);

    // local chunk scans (256 chunks of 8 steps)
    k_phase1<<<dim3(C_CH), 512, 0, stream>>>(Whh_hi, Whh_lo, zout);

    // chunk-carry Kogge-Stone scan (fp32): level l uses shift 2^l,
    // W^(S*2^l) = W^(8*2^l) = Q[2+l], l = 0..7
    k_seed<<<dim3((C_CH * B_ * H_) / 256), 256, 0, stream>>>(h0, zout, Va);
    k_scan<<<dim3(16, C_CH), 256, 0, stream>>>(Va, Q[2], Vb, 1);
    k_scan<<<dim3(16, C_CH), 256, 0, stream>>>(Vb, Q[3], Va, 2);
    k_scan<<<dim3(16, C_CH), 256, 0, stream>>>(Va, Q[4], Vb, 4);
    k_scan<<<dim3(16, C_CH), 256, 0, stream>>>(Vb, Q[5], Va, 8);
    k_scan<<<dim3(16, C_CH), 256, 0, stream>>>(Va, Q[6], Vb, 16);
    k_scan<<<dim3(16, C_CH), 256, 0, stream>>>(Vb, Q[7], Va, 32);
    k_scan<<<dim3(16, C_CH), 256, 0, stream>>>(Va, Q[8], Vb, 64);
    k_scan<<<dim3(16, C_CH), 256, 0, stream>>>(Vb, Q[9], Va, 128);

    // broadcast carries through chunks + finalize z
    k_phase3<<<dim3(C_CH), 512, 0, stream>>>(Whh_hi, Whh_lo, Va, zout);

    // logits + softmax
    k_logits<<<dim3((B_ * T_) / 64), 256, 0, stream>>>(zout, Wlin_hi, blin, out);
}

// Round 2
// 2043.857 us; speedup vs baseline: 1.4558x; 1.1590x over previous
//
#include <hip/hip_runtime.h>
#include <math.h>

// Problem constants
#define B_ 32
#define T_ 2048
#define D_ 256
#define H_ 512
#define O_ 256
#define S_CH 8               // chunk length
#define C_CH 256             // number of chunks = T/S: 1 block per CU

typedef short bf16x8 __attribute__((ext_vector_type(8)));  // 8 bf16 (4 VGPRs) MFMA frag
typedef float f32x4  __attribute__((ext_vector_type(4)));

#define NTL(p)     __builtin_nontemporal_load(p)
#define NTS(v, p)  __builtin_nontemporal_store((v), (p))

__device__ __forceinline__ unsigned short f2bf_rne(float x) {
    unsigned int u = __builtin_bit_cast(unsigned int, x);
    unsigned int r = (u + 0x7fffu + ((u >> 16) & 1u)) >> 16;
    return (unsigned short)r;
}
__device__ __forceinline__ float bf2f(unsigned short h) {
    unsigned int u = ((unsigned int)h) << 16;
    return __builtin_bit_cast(float, u);
}

#define MFMA16(a, b, c) __builtin_amdgcn_mfma_f32_16x16x32_bf16((a), (b), (c), 0, 0, 0)

// Build split-bf16 A-fragments (hi+lo) from 8 consecutive fp32 values.
__device__ __forceinline__ void split_frag(const float* p, bf16x8& hi, bf16x8& lo) {
    f32x4 a = *(const f32x4*)p;
    f32x4 b = *(const f32x4*)(p + 4);
#pragma unroll
    for (int i = 0; i < 4; i++) {
        unsigned short h = f2bf_rne(a[i]);
        hi[i] = (short)h; lo[i] = (short)f2bf_rne(a[i] - bf2f(h));
        unsigned short h2 = f2bf_rne(b[i]);
        hi[4 + i] = (short)h2; lo[4 + i] = (short)f2bf_rne(b[i] - bf2f(h2));
    }
}
// Same, but non-temporal loads (streaming sources: x, zq).
__device__ __forceinline__ void split_frag_nt(const float* p, bf16x8& hi, bf16x8& lo) {
    f32x4 a = NTL((const f32x4*)p);
    f32x4 b = NTL((const f32x4*)(p + 4));
#pragma unroll
    for (int i = 0; i < 4; i++) {
        unsigned short h = f2bf_rne(a[i]);
        hi[i] = (short)h; lo[i] = (short)f2bf_rne(a[i] - bf2f(h));
        unsigned short h2 = f2bf_rne(b[i]);
        hi[4 + i] = (short)h2; lo[4 + i] = (short)f2bf_rne(b[i] - bf2f(h2));
    }
}

// Fragment-major packed offset for a B-matrix element (n, k), KB = K/32.
__device__ __forceinline__ size_t wpack_off(int n, int k, int KB) {
    int n16 = n >> 4, l15 = n & 15;
    int kb = k >> 5, lhi = (k >> 3) & 3, j = k & 7;
    return (((size_t)(n16 * KB + kb) * 4 + lhi) * 16 + l15) * 8 + j;
}

// Same layout for the LDS-resident h state (m over 32 batches, n over 512).
__device__ __forceinline__ int hfrag_off(int m, int n) {
    int m16 = m >> 4, l15m = m & 15;
    int kb = n >> 5, lhi = (n >> 3) & 3, j = n & 7;
    return (((m16 * 16 + kb) * 4 + lhi) * 16 + l15m) * 8 + j;
}

// ---------------------------------------------------------------------------
// Pack fp32 matrix into frag-major bf16 hi/lo. kshift: 9 (K=512) or 8 (K=256).
// ---------------------------------------------------------------------------
__global__ void k_pack(const float* __restrict__ in, unsigned short* __restrict__ hi,
                       unsigned short* __restrict__ lo, int total, int kshift) {
    int i = blockIdx.x * 256 + threadIdx.x;
    if (i < total) {
        int n = i >> kshift;
        int k = i & ((1 << kshift) - 1);
        float v = in[i];
        unsigned short h = f2bf_rne(v);
        size_t o = wpack_off(n, k, 1 << (kshift - 5));
        hi[o] = h;
        lo[o] = f2bf_rne(v - bf2f(h));
    }
}

// ---------------------------------------------------------------------------
// fp32 matrix square: Out = In * In  (512x512), grid (16,16), block 256
// ---------------------------------------------------------------------------
__global__ __launch_bounds__(256) void k_sq(const float* __restrict__ In, float* __restrict__ Out) {
    __shared__ float As[32][33];
    __shared__ float Bs[32][33];
    int tx = threadIdx.x & 15, ty = threadIdx.x >> 4;
    int j0 = blockIdx.x * 32, i0 = blockIdx.y * 32;
    float a00 = 0.f, a01 = 0.f, a10 = 0.f, a11 = 0.f;
    int r  = threadIdx.x >> 3;
    int c4 = (threadIdx.x & 7) * 4;
    for (int kb = 0; kb < H_ / 32; kb++) {
        f32x4 va = *(const f32x4*)(In + (size_t)(i0 + r) * H_ + kb * 32 + c4);
        f32x4 vb = *(const f32x4*)(In + (size_t)(kb * 32 + r) * H_ + j0 + c4);
        __syncthreads();
        As[r][c4 + 0] = va[0]; As[r][c4 + 1] = va[1]; As[r][c4 + 2] = va[2]; As[r][c4 + 3] = va[3];
        Bs[r][c4 + 0] = vb[0]; Bs[r][c4 + 1] = vb[1]; Bs[r][c4 + 2] = vb[2]; Bs[r][c4 + 3] = vb[3];
        __syncthreads();
#pragma unroll
        for (int k = 0; k < 32; k++) {
            float b0 = Bs[k][tx * 2], b1 = Bs[k][tx * 2 + 1];
            float a0 = As[ty * 2][k], a1 = As[ty * 2 + 1][k];
            a00 += a0 * b0; a01 += a0 * b1; a10 += a1 * b0; a11 += a1 * b1;
        }
    }
    Out[(size_t)(i0 + ty * 2) * H_ + j0 + tx * 2]     = a00;
    Out[(size_t)(i0 + ty * 2) * H_ + j0 + tx * 2 + 1] = a01;
    Out[(size_t)(i0 + ty * 2 + 1) * H_ + j0 + tx * 2]     = a10;
    Out[(size_t)(i0 + ty * 2 + 1) * H_ + j0 + tx * 2 + 1] = a11;
}

// ---------------------------------------------------------------------------
// Seed the chunk-carry scan inputs: v[0]=h0, v[c]=l_end(c-1) from zb.
// ---------------------------------------------------------------------------
__global__ void k_seed(const float* __restrict__ h0, const float* __restrict__ zb,
                       float* __restrict__ Va) {
    int i = blockIdx.x * 256 + threadIdx.x;  // over C*B*H
    int c = i >> 14;             // B*H = 16384
    int bn = i & 16383;
    int b = bn >> 9, n = bn & 511;
    float v = (c == 0) ? h0[bn] : NTL(zb + ((size_t)b * T_ + (c * S_CH - 1)) * H_ + n);
    NTS(v, Va + i);
}

// ---------------------------------------------------------------------------
// One Kogge-Stone scan level via split-bf16 MFMA:
// Vout[c] = Vin[c] + Vin[c-s] @ (W^(S*s))^T  (c >= s), else copy.
// Weights pre-packed frag-major (Qp_hi/lo). grid C_CH, block 512 (8 waves).
// Same MFMA body / layouts as k_phase3. V traffic non-temporal.
// ---------------------------------------------------------------------------
__global__ __launch_bounds__(512) void k_scan2(const float* __restrict__ Vin,
                                               const unsigned short* __restrict__ Qp_hi,
                                               const unsigned short* __restrict__ Qp_lo,
                                               float* __restrict__ Vout, int s) {
    __shared__ __attribute__((aligned(16))) unsigned short hA[16384];
    __shared__ __attribute__((aligned(16))) unsigned short lA[16384];
    int c = blockIdx.x;
    int w = threadIdx.x >> 6;
    int lane = threadIdx.x & 63;
    int l15 = lane & 15, lhi = lane >> 4;

    if (c < s) {  // pure copy
        size_t base = (size_t)c * B_ * H_;
        for (int i = threadIdx.x * 4; i < B_ * H_; i += 2048) {
            f32x4 v = NTL((const f32x4*)(Vin + base + i));
            NTS(v, (f32x4*)(Vout + base + i));
        }
        return;
    }

    // stage Vin[c-s] as split-bf16 frag-major in LDS
    size_t src = (size_t)(c - s) * B_ * H_;
    for (int i = threadIdx.x; i < 16384; i += 512) {
        float v = NTL(Vin + src + i);          // i = m*512 + n, row-major
        int m = i >> 9, n = i & 511;
        unsigned short hi = f2bf_rne(v);
        int o = hfrag_off(m, n);
        hA[o] = hi;
        lA[o] = f2bf_rne(v - bf2f(hi));
    }
    __syncthreads();

    // issue the additive Vin[c] loads early (overlap with MFMA)
    size_t dst = (size_t)c * B_ * H_;
    float ad[2][4][4];
#pragma unroll
    for (int mt = 0; mt < 2; mt++)
#pragma unroll
        for (int nt = 0; nt < 4; nt++) {
            int n = w * 64 + nt * 16 + l15;
#pragma unroll
            for (int r = 0; r < 4; r++) {
                int m = mt * 16 + lhi * 4 + r;
                ad[mt][nt][r] = NTL(Vin + dst + (size_t)m * H_ + n);
            }
        }

    f32x4 acc[2][4];
#pragma unroll
    for (int mt = 0; mt < 2; mt++)
#pragma unroll
        for (int nt = 0; nt < 4; nt++) acc[mt][nt] = (f32x4){0.f, 0.f, 0.f, 0.f};

    for (int kb = 0; kb < 16; kb++) {
        bf16x8 ah0 = *(const bf16x8*)&hA[(kb << 9) + lane * 8];
        bf16x8 ah1 = *(const bf16x8*)&hA[((16 + kb) << 9) + lane * 8];
        bf16x8 al0 = *(const bf16x8*)&lA[(kb << 9) + lane * 8];
        bf16x8 al1 = *(const bf16x8*)&lA[((16 + kb) << 9) + lane * 8];
#pragma unroll
        for (int nt = 0; nt < 4; nt++) {
            size_t wb = (((size_t)(w * 4 + nt) * 16 + kb) << 9) + lane * 8;
            bf16x8 bh = *(const bf16x8*)(Qp_hi + wb);
            bf16x8 bl = *(const bf16x8*)(Qp_lo + wb);
            acc[0][nt] = MFMA16(ah0, bh, acc[0][nt]);
            acc[0][nt] = MFMA16(al0, bh, acc[0][nt]);
            acc[0][nt] = MFMA16(ah0, bl, acc[0][nt]);
            acc[1][nt] = MFMA16(ah1, bh, acc[1][nt]);
            acc[1][nt] = MFMA16(al1, bh, acc[1][nt]);
            acc[1][nt] = MFMA16(ah1, bl, acc[1][nt]);
        }
    }
#pragma unroll
    for (int mt = 0; mt < 2; mt++)
#pragma unroll
        for (int nt = 0; nt < 4; nt++) {
            int n = w * 64 + nt * 16 + l15;
#pragma unroll
            for (int r = 0; r < 4; r++) {
                int m = mt * 16 + lhi * 4 + r;
                NTS(acc[mt][nt][r] + ad[mt][nt][r], Vout + dst + (size_t)m * H_ + n);
            }
        }
}

// ---------------------------------------------------------------------------
// K0: zb[b][t][h] = x[b][t][:] @ W_ih^T + (b_ih + b_hh), fp32, into the z
// region of d_out. x split hi/lo on the fly; W_ih pre-split+packed; 3 MFMAs.
// grid (T/64, B), block 512 (8 waves; wave w owns n-slice 64w..64w+63)
// ---------------------------------------------------------------------------
__global__ __launch_bounds__(512) void k_xw(const float* __restrict__ x,
                                            const unsigned short* __restrict__ Wp_hi,
                                            const unsigned short* __restrict__ Wp_lo,
                                            const float* __restrict__ bih,
                                            const float* __restrict__ bhh,
                                            float* __restrict__ zb) {
    int b  = blockIdx.y;
    int t0 = blockIdx.x * 64;
    int w    = threadIdx.x >> 6;
    int lane = threadIdx.x & 63;
    int l15 = lane & 15, lhi = lane >> 4;
    int nb = w * 64;

    f32x4 acc[4][4];  // [mt][nt]
    for (int mt = 0; mt < 4; mt++)
        for (int nt = 0; nt < 4; nt++)
            acc[mt][nt] = (f32x4){0.f, 0.f, 0.f, 0.f};

    const float* xb = x + (size_t)b * T_ * D_;
    for (int kb = 0; kb < D_ / 32; kb++) {
        int kofs = kb * 32 + lhi * 8;
        bf16x8 ah[4], al[4];
#pragma unroll
        for (int mt = 0; mt < 4; mt++) {
            int t = t0 + mt * 16 + l15;
            split_frag_nt(xb + (size_t)t * D_ + kofs, ah[mt], al[mt]);
        }
#pragma unroll
        for (int nt = 0; nt < 4; nt++) {
            size_t wb = (((size_t)(w * 4 + nt) * 8 + kb) << 9) + lane * 8;  // KB=8
            bf16x8 bh = *(const bf16x8*)(Wp_hi + wb);
            bf16x8 bl = *(const bf16x8*)(Wp_lo + wb);
#pragma unroll
            for (int mt = 0; mt < 4; mt++) {
                acc[mt][nt] = MFMA16(ah[mt], bh, acc[mt][nt]);
                acc[mt][nt] = MFMA16(al[mt], bh, acc[mt][nt]);
                acc[mt][nt] = MFMA16(ah[mt], bl, acc[mt][nt]);
            }
        }
    }
#pragma unroll
    for (int nt = 0; nt < 4; nt++) {
        int n = nb + nt * 16 + l15;
        float bias = bih[n] + bhh[n];
#pragma unroll
        for (int mt = 0; mt < 4; mt++) {
#pragma unroll
            for (int r = 0; r < 4; r++) {
                int t = t0 + mt * 16 + lhi * 4 + r;
                NTS(acc[mt][nt][r] + bias, zb + ((size_t)b * T_ + t) * H_ + n);
            }
        }
    }
}

// ---------------------------------------------------------------------------
// Phase 1: per-chunk local recurrence l_t = xw_t + l_{t-1} @ W_hh^T (from 0),
// in place over zb (fp32, [b][t][h]). State fp32 via split-bf16 hi/lo LDS.
// zb traffic non-temporal (keeps packed Whh resident in L2).
// grid C_CH, block 512.
// ---------------------------------------------------------------------------
__global__ __launch_bounds__(512) void k_phase1(const unsigned short* __restrict__ Wp_hi,
                                                const unsigned short* __restrict__ Wp_lo,
                                                float* __restrict__ zb) {
    __shared__ __attribute__((aligned(16))) unsigned short hA[16384];
    __shared__ __attribute__((aligned(16))) unsigned short lA[16384];
    int c = blockIdx.x;
    int w = threadIdx.x >> 6;
    int lane = threadIdx.x & 63;
    int l15 = lane & 15, lhi = lane >> 4;

    for (int i = threadIdx.x; i < 16384; i += 512) { hA[i] = 0; lA[i] = 0; }
    __syncthreads();

    for (int j = 0; j < S_CH; j++) {
        int t = c * S_CH + j;
        // issue this step's xw loads early; they resolve under the MFMA loop
        float xw[2][4][4];
#pragma unroll
        for (int mt = 0; mt < 2; mt++)
#pragma unroll
            for (int nt = 0; nt < 4; nt++) {
                int n = w * 64 + nt * 16 + l15;
#pragma unroll
                for (int r = 0; r < 4; r++) {
                    int b = mt * 16 + lhi * 4 + r;
                    xw[mt][nt][r] = NTL(zb + ((size_t)b * T_ + t) * H_ + n);
                }
            }
        f32x4 acc[2][4];
#pragma unroll
        for (int mt = 0; mt < 2; mt++)
#pragma unroll
            for (int nt = 0; nt < 4; nt++) acc[mt][nt] = (f32x4){0.f, 0.f, 0.f, 0.f};
        if (j > 0) {
            for (int kb = 0; kb < 16; kb++) {
                bf16x8 ah0 = *(const bf16x8*)&hA[(kb << 9) + lane * 8];
                bf16x8 ah1 = *(const bf16x8*)&hA[((16 + kb) << 9) + lane * 8];
                bf16x8 al0 = *(const bf16x8*)&lA[(kb << 9) + lane * 8];
                bf16x8 al1 = *(const bf16x8*)&lA[((16 + kb) << 9) + lane * 8];
#pragma unroll
                for (int nt = 0; nt < 4; nt++) {
                    size_t wb = (((size_t)(w * 4 + nt) * 16 + kb) << 9) + lane * 8;
                    bf16x8 bh = *(const bf16x8*)(Wp_hi + wb);
                    bf16x8 bl = *(const bf16x8*)(Wp_lo + wb);
                    acc[0][nt] = MFMA16(ah0, bh, acc[0][nt]);
                    acc[0][nt] = MFMA16(al0, bh, acc[0][nt]);
                    acc[0][nt] = MFMA16(ah0, bl, acc[0][nt]);
                    acc[1][nt] = MFMA16(ah1, bh, acc[1][nt]);
                    acc[1][nt] = MFMA16(al1, bh, acc[1][nt]);
                    acc[1][nt] = MFMA16(ah1, bl, acc[1][nt]);
                }
            }
        }
        __syncthreads();  // all waves done reading previous h before overwrite
#pragma unroll
        for (int mt = 0; mt < 2; mt++) {
#pragma unroll
            for (int nt = 0; nt < 4; nt++) {
                int n = w * 64 + nt * 16 + l15;
#pragma unroll
                for (int r = 0; r < 4; r++) {
                    int b = mt * 16 + lhi * 4 + r;
                    float v = acc[mt][nt][r] + xw[mt][nt][r];
                    NTS(v, zb + ((size_t)b * T_ + t) * H_ + n);  // l_t (fp32)
                    unsigned short hi = f2bf_rne(v);
                    int o = hfrag_off(b, n);
                    hA[o] = hi;
                    lA[o] = f2bf_rne(v - bf2f(hi));
                }
            }
        }
        __syncthreads();
    }
}

// ---------------------------------------------------------------------------
// Phase 3: z_t = l_t + W^{j+1}.Hin[c], v <- W.v per step (split-bf16 MFMA).
// Reads l_t (fp32) from zb and overwrites with final z_t (fp32) in place.
// zb/Hin traffic non-temporal. grid C_CH, block 512.
// ---------------------------------------------------------------------------
__global__ __launch_bounds__(512) void k_phase3(const unsigned short* __restrict__ Wp_hi,
                                                const unsigned short* __restrict__ Wp_lo,
                                                const float* __restrict__ Hin,
                                                float* __restrict__ zb) {
    __shared__ __attribute__((aligned(16))) unsigned short hA[16384];
    __shared__ __attribute__((aligned(16))) unsigned short lA[16384];
    int c = blockIdx.x;
    int w = threadIdx.x >> 6;
    int lane = threadIdx.x & 63;
    int l15 = lane & 15, lhi = lane >> 4;

    for (int i = threadIdx.x; i < 16384; i += 512) {
        float v = NTL(Hin + (size_t)c * B_ * H_ + i);   // i = m*512 + n
        int m = i >> 9, n = i & 511;
        unsigned short hi = f2bf_rne(v);
        int o = hfrag_off(m, n);
        hA[o] = hi;
        lA[o] = f2bf_rne(v - bf2f(hi));
    }
    __syncthreads();

    for (int j = 0; j < S_CH; j++) {
        int t = c * S_CH + j;
        // issue this step's l_t loads early
        float lt[2][4][4];
#pragma unroll
        for (int mt = 0; mt < 2; mt++)
#pragma unroll
            for (int nt = 0; nt < 4; nt++) {
                int n = w * 64 + nt * 16 + l15;
#pragma unroll
                for (int r = 0; r < 4; r++) {
                    int b = mt * 16 + lhi * 4 + r;
                    lt[mt][nt][r] = NTL(zb + ((size_t)b * T_ + t) * H_ + n);
                }
            }
        f32x4 acc[2][4];
#pragma unroll
        for (int mt = 0; mt < 2; mt++)
#pragma unroll
            for (int nt = 0; nt < 4; nt++) acc[mt][nt] = (f32x4){0.f, 0.f, 0.f, 0.f};
        for (int kb = 0; kb < 16; kb++) {
            bf16x8 ah0 = *(const bf16x8*)&hA[(kb << 9) + lane * 8];
            bf16x8 ah1 = *(const bf16x8*)&hA[((16 + kb) << 9) + lane * 8];
            bf16x8 al0 = *(const bf16x8*)&lA[(kb << 9) + lane * 8];
            bf16x8 al1 = *(const bf16x8*)&lA[((16 + kb) << 9) + lane * 8];
#pragma unroll
            for (int nt = 0; nt < 4; nt++) {
                size_t wb = (((size_t)(w * 4 + nt) * 16 + kb) << 9) + lane * 8;
                bf16x8 bh = *(const bf16x8*)(Wp_hi + wb);
                bf16x8 bl = *(const bf16x8*)(Wp_lo + wb);
                acc[0][nt] = MFMA16(ah0, bh, acc[0][nt]);
                acc[0][nt] = MFMA16(al0, bh, acc[0][nt]);
                acc[0][nt] = MFMA16(ah0, bl, acc[0][nt]);
                acc[1][nt] = MFMA16(ah1, bh, acc[1][nt]);
                acc[1][nt] = MFMA16(al1, bh, acc[1][nt]);
                acc[1][nt] = MFMA16(ah1, bl, acc[1][nt]);
            }
        }
        __syncthreads();
#pragma unroll
        for (int mt = 0; mt < 2; mt++) {
#pragma unroll
            for (int nt = 0; nt < 4; nt++) {
                int n = w * 64 + nt * 16 + l15;
#pragma unroll
                for (int r = 0; r < 4; r++) {
                    int b = mt * 16 + lhi * 4 + r;
                    float vv = acc[mt][nt][r];
                    NTS(vv + lt[mt][nt][r], zb + ((size_t)b * T_ + t) * H_ + n);
                    unsigned short hi = f2bf_rne(vv);
                    int o = hfrag_off(b, n);
                    hA[o] = hi;
                    lA[o] = f2bf_rne(vv - bf2f(hi));
                }
            }
        }
        __syncthreads();
    }
}

// ---------------------------------------------------------------------------
// K5: logits = z @ W_lin^T + b_lin, fused softmax over O=256, fp32 out.
// grid (B*T/64), block 256 (4 waves; wave w owns rows 16w..16w+15, all cols).
// ---------------------------------------------------------------------------
__global__ __launch_bounds__(256) void k_logits(const float* __restrict__ zq,
                                                const unsigned short* __restrict__ Wp_hi,
                                                const float* __restrict__ blin,
                                                float* __restrict__ out) {
    size_t row0 = (size_t)blockIdx.x * 64;
    int w = threadIdx.x >> 6, lane = threadIdx.x & 63;
    int l15 = lane & 15, lhi = lane >> 4;

    f32x4 acc[16];
#pragma unroll
    for (int nt = 0; nt < 16; nt++) acc[nt] = (f32x4){0.f, 0.f, 0.f, 0.f};

    const float* arow = zq + (row0 + (size_t)w * 16 + l15) * H_;
    for (int kb = 0; kb < 16; kb++) {
        int kofs = kb * 32 + lhi * 8;
        bf16x8 ah, al;
        split_frag_nt(arow + kofs, ah, al);
#pragma unroll
        for (int nt = 0; nt < 16; nt++) {
            size_t wb = (((size_t)nt * 16 + kb) << 9) + lane * 8;  // n16 = nt, KB=16
            bf16x8 bh = *(const bf16x8*)(Wp_hi + wb);
            acc[nt] = MFMA16(ah, bh, acc[nt]);
            acc[nt] = MFMA16(al, bh, acc[nt]);
        }
    }
#pragma unroll
    for (int nt = 0; nt < 16; nt++) {
        float bb = blin[nt * 16 + l15];
#pragma unroll
        for (int r = 0; r < 4; r++) acc[nt][r] += bb;
    }
    float rmax[4], rinv[4];
#pragma unroll
    for (int r = 0; r < 4; r++) {
        float mx = -INFINITY;
#pragma unroll
        for (int nt = 0; nt < 16; nt++) mx = fmaxf(mx, acc[nt][r]);
        for (int s = 1; s < 16; s <<= 1) mx = fmaxf(mx, __shfl_xor(mx, s));
        float sum = 0.f;
#pragma unroll
        for (int nt = 0; nt < 16; nt++) sum += __expf(acc[nt][r] - mx);
        for (int s = 1; s < 16; s <<= 1) sum += __shfl_xor(sum, s);
        rmax[r] = mx;
        rinv[r] = 1.f / sum;
    }
#pragma unroll
    for (int nt = 0; nt < 16; nt++) {
#pragma unroll
        for (int r = 0; r < 4; r++) {
            float e = __expf(acc[nt][r] - rmax[r]) * rinv[r];
            size_t row = row0 + (size_t)w * 16 + lhi * 4 + r;
            NTS(e, out + row * O_ + nt * 16 + l15);
        }
    }
}

// ---------------------------------------------------------------------------
extern "C" void kernel_launch(void* const* d_in, const int* in_sizes, int n_in,
                              void* d_out, int out_size, void* d_ws, size_t ws_size,
                              hipStream_t stream) {
    const float* x    = (const float*)d_in[0];
    const float* h0   = (const float*)d_in[1];
    const float* Wih  = (const float*)d_in[2];
    const float* Whh  = (const float*)d_in[3];
    const float* bih  = (const float*)d_in[4];
    const float* bhh  = (const float*)d_in[5];
    const float* Wlin = (const float*)d_in[6];
    const float* blin = (const float*)d_in[7];

    float* out  = (float*)d_out;
    float* zout = out + (size_t)B_ * T_ * O_;  // z region of d_out (fp32, in-place scan)

    // ws layout: Q[0..9] (W^2..W^1024) | packed bf16 splits | packed Q levels.
    // ~20 MB total. Va/Vb (16 MB each) live in the softmax-out region of
    // d_out, which is dead until k_logits (the final launch).
    float* ws = (float*)d_ws;
    float* Q[10];
    for (int i = 0; i < 10; i++) Q[i] = ws + (size_t)i * H_ * H_;
    unsigned short* Whh_hi = (unsigned short*)(ws + (size_t)10 * H_ * H_);
    unsigned short* Whh_lo = Whh_hi + (size_t)H_ * H_;
    unsigned short* Wih_hi = Whh_lo + (size_t)H_ * H_;
    unsigned short* Wih_lo = Wih_hi + (size_t)H_ * D_;
    unsigned short* Wlin_hi = Wih_lo + (size_t)H_ * D_;
    unsigned short* Wlin_lo = Wlin_hi + (size_t)O_ * H_;
    unsigned short* Qp_hi   = Wlin_lo + (size_t)O_ * H_;   // 8 levels x H*H
    unsigned short* Qp_lo   = Qp_hi + (size_t)8 * H_ * H_;

    float* Va = out;                            // 16 MB, dead until k_logits
    float* Vb = out + (size_t)C_CH * B_ * H_;   // 16 MB, ends at 32 MB < 64 MB

    // Pack weights (frag-major, bf16 hi/lo)
    k_pack<<<dim3((H_ * H_) / 256), 256, 0, stream>>>(Whh, Whh_hi, Whh_lo, H_ * H_, 9);
    k_pack<<<dim3((H_ * D_) / 256), 256, 0, stream>>>(Wih, Wih_hi, Wih_lo, H_ * D_, 8);
    k_pack<<<dim3((O_ * H_) / 256), 256, 0, stream>>>(Wlin, Wlin_hi, Wlin_lo, O_ * H_, 9);

    // Squaring chain: Q[i] = W^(2^(i+1)), i=0..9  (W^2 .. W^1024)
    k_sq<<<dim3(16, 16), 256, 0, stream>>>(Whh, Q[0]);
    for (int i = 1; i < 10; i++)
        k_sq<<<dim3(16, 16), 256, 0, stream>>>(Q[i - 1], Q[i]);

    // Pack the 8 scan-level matrices W^(8*2^l) = Q[2+l], l=0..7
    for (int l = 0; l < 8; l++)
        k_pack<<<dim3((H_ * H_) / 256), 256, 0, stream>>>(
            Q[2 + l], Qp_hi + (size_t)l * H_ * H_, Qp_lo + (size_t)l * H_ * H_, H_ * H_, 9);

    // xw into z region
    k_xw<<<dim3(T_ / 64, B_), 512, 0, stream>>>(x, Wih_hi, Wih_lo, bih, bhh, zout);

    // local chunk scans (256 chunks of 8 steps)
    k_phase1<<<dim3(C_CH), 512, 0, stream>>>(Whh_hi, Whh_lo, zout);

    // chunk-carry Kogge-Stone scan (split-bf16 MFMA): level l shift 2^l
    k_seed<<<dim3((C_CH * B_ * H_) / 256), 256, 0, stream>>>(h0, zout, Va);
    {
        float* vin = Va;
        float* vout = Vb;
        int s = 1;
        for (int l = 0; l < 8; l++) {
            k_scan2<<<dim3(C_CH), 512, 0, stream>>>(
                vin, Qp_hi + (size_t)l * H_ * H_, Qp_lo + (size_t)l * H_ * H_, vout, s);
            float* tmp = vin; vin = vout; vout = tmp;
            s <<= 1;
        }
        // 8 swaps -> final result back in Va
    }

    // broadcast carries through chunks + finalize z
    k_phase3<<<dim3(C_CH), 512, 0, stream>>>(Whh_hi, Whh_lo, Va, zout);

    // logits + softmax
    k_logits<<<dim3((B_ * T_) / 64), 256, 0, stream>>>(zout, Wlin_hi, blin, out);
}

// Round 3
// 1602.887 us; speedup vs baseline: 1.8564x; 1.2751x over previous
//
#include <hip/hip_runtime.h>
#include <math.h>

// Problem constants
#define B_ 32
#define T_ 2048
#define D_ 256
#define H_ 512
#define O_ 256
#define S_CH 8               // chunk length
#define C_CH 256             // number of chunks = T/S: 1 block per CU

typedef short bf16x8 __attribute__((ext_vector_type(8)));  // 8 bf16 (4 VGPRs) MFMA frag
typedef float f32x4  __attribute__((ext_vector_type(4)));

#define NTL(p)     __builtin_nontemporal_load(p)

__device__ __forceinline__ unsigned short f2bf_rne(float x) {
    unsigned int u = __builtin_bit_cast(unsigned int, x);
    unsigned int r = (u + 0x7fffu + ((u >> 16) & 1u)) >> 16;
    return (unsigned short)r;
}
__device__ __forceinline__ float bf2f(unsigned short h) {
    unsigned int u = ((unsigned int)h) << 16;
    return __builtin_bit_cast(float, u);
}

#define MFMA16(a, b, c) __builtin_amdgcn_mfma_f32_16x16x32_bf16((a), (b), (c), 0, 0, 0)

// Build split-bf16 A-fragments (hi+lo) from 8 consecutive fp32 values.
__device__ __forceinline__ void split_frag(const float* p, bf16x8& hi, bf16x8& lo) {
    f32x4 a = *(const f32x4*)p;
    f32x4 b = *(const f32x4*)(p + 4);
#pragma unroll
    for (int i = 0; i < 4; i++) {
        unsigned short h = f2bf_rne(a[i]);
        hi[i] = (short)h; lo[i] = (short)f2bf_rne(a[i] - bf2f(h));
        unsigned short h2 = f2bf_rne(b[i]);
        hi[4 + i] = (short)h2; lo[4 + i] = (short)f2bf_rne(b[i] - bf2f(h2));
    }
}
// Same, but non-temporal loads (pure read-once streams: x, zq).
__device__ __forceinline__ void split_frag_nt(const float* p, bf16x8& hi, bf16x8& lo) {
    f32x4 a = NTL((const f32x4*)p);
    f32x4 b = NTL((const f32x4*)(p + 4));
#pragma unroll
    for (int i = 0; i < 4; i++) {
        unsigned short h = f2bf_rne(a[i]);
        hi[i] = (short)h; lo[i] = (short)f2bf_rne(a[i] - bf2f(h));
        unsigned short h2 = f2bf_rne(b[i]);
        hi[4 + i] = (short)h2; lo[4 + i] = (short)f2bf_rne(b[i] - bf2f(h2));
    }
}

// Fragment-major packed offset for a B-matrix element (n, k), KB = K/32.
__device__ __forceinline__ size_t wpack_off(int n, int k, int KB) {
    int n16 = n >> 4, l15 = n & 15;
    int kb = k >> 5, lhi = (k >> 3) & 3, j = k & 7;
    return (((size_t)(n16 * KB + kb) * 4 + lhi) * 16 + l15) * 8 + j;
}

// Same layout for the LDS-resident h state (m over 32 batches, n over 512).
__device__ __forceinline__ int hfrag_off(int m, int n) {
    int m16 = m >> 4, l15m = m & 15;
    int kb = n >> 5, lhi = (n >> 3) & 3, j = n & 7;
    return (((m16 * 16 + kb) * 4 + lhi) * 16 + l15m) * 8 + j;
}

// ---------------------------------------------------------------------------
// Pack fp32 matrix into frag-major bf16 hi/lo. kshift: 9 (K=512) or 8 (K=256).
// ---------------------------------------------------------------------------
__global__ void k_pack(const float* __restrict__ in, unsigned short* __restrict__ hi,
                       unsigned short* __restrict__ lo, int total, int kshift) {
    int i = blockIdx.x * 256 + threadIdx.x;
    if (i < total) {
        int n = i >> kshift;
        int k = i & ((1 << kshift) - 1);
        float v = in[i];
        unsigned short h = f2bf_rne(v);
        size_t o = wpack_off(n, k, 1 << (kshift - 5));
        hi[o] = h;
        lo[o] = f2bf_rne(v - bf2f(h));
    }
}

// ---------------------------------------------------------------------------
// fp32 matmul: Out = A * Bm  (512x512 row-major), grid (16,16), block 256
// ---------------------------------------------------------------------------
__global__ __launch_bounds__(256) void k_mul(const float* __restrict__ A,
                                             const float* __restrict__ Bm,
                                             float* __restrict__ Out) {
    __shared__ float As[32][33];
    __shared__ float Bs[32][33];
    int tx = threadIdx.x & 15, ty = threadIdx.x >> 4;
    int j0 = blockIdx.x * 32, i0 = blockIdx.y * 32;
    float a00 = 0.f, a01 = 0.f, a10 = 0.f, a11 = 0.f;
    int r  = threadIdx.x >> 3;
    int c4 = (threadIdx.x & 7) * 4;
    for (int kb = 0; kb < H_ / 32; kb++) {
        f32x4 va = *(const f32x4*)(A + (size_t)(i0 + r) * H_ + kb * 32 + c4);
        f32x4 vb = *(const f32x4*)(Bm + (size_t)(kb * 32 + r) * H_ + j0 + c4);
        __syncthreads();
        As[r][c4 + 0] = va[0]; As[r][c4 + 1] = va[1]; As[r][c4 + 2] = va[2]; As[r][c4 + 3] = va[3];
        Bs[r][c4 + 0] = vb[0]; Bs[r][c4 + 1] = vb[1]; Bs[r][c4 + 2] = vb[2]; Bs[r][c4 + 3] = vb[3];
        __syncthreads();
#pragma unroll
        for (int k = 0; k < 32; k++) {
            float b0 = Bs[k][tx * 2], b1 = Bs[k][tx * 2 + 1];
            float a0 = As[ty * 2][k], a1 = As[ty * 2 + 1][k];
            a00 += a0 * b0; a01 += a0 * b1; a10 += a1 * b0; a11 += a1 * b1;
        }
    }
    Out[(size_t)(i0 + ty * 2) * H_ + j0 + tx * 2]     = a00;
    Out[(size_t)(i0 + ty * 2) * H_ + j0 + tx * 2 + 1] = a01;
    Out[(size_t)(i0 + ty * 2 + 1) * H_ + j0 + tx * 2]     = a10;
    Out[(size_t)(i0 + ty * 2 + 1) * H_ + j0 + tx * 2 + 1] = a11;
}

// ---------------------------------------------------------------------------
// Seed the chunk-carry scan inputs: v[0]=h0, v[c]=l_end(c-1) from zb.
// ---------------------------------------------------------------------------
__global__ void k_seed(const float* __restrict__ h0, const float* __restrict__ zb,
                       float* __restrict__ Va) {
    int i = blockIdx.x * 256 + threadIdx.x;  // over C*B*H
    int c = i >> 14;             // B*H = 16384
    int bn = i & 16383;
    int b = bn >> 9, n = bn & 511;
    Va[i] = (c == 0) ? h0[bn] : zb[((size_t)b * T_ + (c * S_CH - 1)) * H_ + n];
}

// ---------------------------------------------------------------------------
// One Kogge-Stone scan level via split-bf16 MFMA:
// Vout[c] = Vin[c] + Vin[c-s] @ (W^(S*s))^T  (c >= s), else copy.
// Weights pre-packed frag-major (Qp_hi/lo). grid C_CH, block 512 (8 waves).
// ---------------------------------------------------------------------------
__global__ __launch_bounds__(512) void k_scan2(const float* __restrict__ Vin,
                                               const unsigned short* __restrict__ Qp_hi,
                                               const unsigned short* __restrict__ Qp_lo,
                                               float* __restrict__ Vout, int s) {
    __shared__ __attribute__((aligned(16))) unsigned short hA[16384];
    __shared__ __attribute__((aligned(16))) unsigned short lA[16384];
    int c = blockIdx.x;
    int w = threadIdx.x >> 6;
    int lane = threadIdx.x & 63;
    int l15 = lane & 15, lhi = lane >> 4;

    if (c < s) {  // pure copy
        size_t base = (size_t)c * B_ * H_;
        for (int i = threadIdx.x * 4; i < B_ * H_; i += 2048) {
            f32x4 v = *(const f32x4*)(Vin + base + i);
            *(f32x4*)(Vout + base + i) = v;
        }
        return;
    }

    // stage Vin[c-s] as split-bf16 frag-major in LDS
    size_t src = (size_t)(c - s) * B_ * H_;
    for (int i = threadIdx.x; i < 16384; i += 512) {
        float v = Vin[src + i];               // i = m*512 + n, row-major
        int m = i >> 9, n = i & 511;
        unsigned short hi = f2bf_rne(v);
        int o = hfrag_off(m, n);
        hA[o] = hi;
        lA[o] = f2bf_rne(v - bf2f(hi));
    }
    __syncthreads();

    // issue the additive Vin[c] loads early (overlap with MFMA)
    size_t dst = (size_t)c * B_ * H_;
    float ad[2][4][4];
#pragma unroll
    for (int mt = 0; mt < 2; mt++)
#pragma unroll
        for (int nt = 0; nt < 4; nt++) {
            int n = w * 64 + nt * 16 + l15;
#pragma unroll
            for (int r = 0; r < 4; r++) {
                int m = mt * 16 + lhi * 4 + r;
                ad[mt][nt][r] = Vin[dst + (size_t)m * H_ + n];
            }
        }

    f32x4 acc[2][4];
#pragma unroll
    for (int mt = 0; mt < 2; mt++)
#pragma unroll
        for (int nt = 0; nt < 4; nt++) acc[mt][nt] = (f32x4){0.f, 0.f, 0.f, 0.f};

    for (int kb = 0; kb < 16; kb++) {
        bf16x8 ah0 = *(const bf16x8*)&hA[(kb << 9) + lane * 8];
        bf16x8 ah1 = *(const bf16x8*)&hA[((16 + kb) << 9) + lane * 8];
        bf16x8 al0 = *(const bf16x8*)&lA[(kb << 9) + lane * 8];
        bf16x8 al1 = *(const bf16x8*)&lA[((16 + kb) << 9) + lane * 8];
#pragma unroll
        for (int nt = 0; nt < 4; nt++) {
            size_t wb = (((size_t)(w * 4 + nt) * 16 + kb) << 9) + lane * 8;
            bf16x8 bh = *(const bf16x8*)(Qp_hi + wb);
            bf16x8 bl = *(const bf16x8*)(Qp_lo + wb);
            acc[0][nt] = MFMA16(ah0, bh, acc[0][nt]);
            acc[0][nt] = MFMA16(al0, bh, acc[0][nt]);
            acc[0][nt] = MFMA16(ah0, bl, acc[0][nt]);
            acc[1][nt] = MFMA16(ah1, bh, acc[1][nt]);
            acc[1][nt] = MFMA16(al1, bh, acc[1][nt]);
            acc[1][nt] = MFMA16(ah1, bl, acc[1][nt]);
        }
    }
#pragma unroll
    for (int mt = 0; mt < 2; mt++)
#pragma unroll
        for (int nt = 0; nt < 4; nt++) {
            int n = w * 64 + nt * 16 + l15;
#pragma unroll
            for (int r = 0; r < 4; r++) {
                int m = mt * 16 + lhi * 4 + r;
                Vout[dst + (size_t)m * H_ + n] = acc[mt][nt][r] + ad[mt][nt][r];
            }
        }
}

// ---------------------------------------------------------------------------
// K0: zb[b][t][h] = x[b][t][:] @ W_ih^T + (b_ih + b_hh), fp32, into the z
// region of d_out. x split hi/lo on the fly; W_ih pre-split+packed; 3 MFMAs.
// grid (T/64, B), block 512 (8 waves; wave w owns n-slice 64w..64w+63)
// ---------------------------------------------------------------------------
__global__ __launch_bounds__(512) void k_xw(const float* __restrict__ x,
                                            const unsigned short* __restrict__ Wp_hi,
                                            const unsigned short* __restrict__ Wp_lo,
                                            const float* __restrict__ bih,
                                            const float* __restrict__ bhh,
                                            float* __restrict__ zb) {
    int b  = blockIdx.y;
    int t0 = blockIdx.x * 64;
    int w    = threadIdx.x >> 6;
    int lane = threadIdx.x & 63;
    int l15 = lane & 15, lhi = lane >> 4;
    int nb = w * 64;

    f32x4 acc[4][4];  // [mt][nt]
    for (int mt = 0; mt < 4; mt++)
        for (int nt = 0; nt < 4; nt++)
            acc[mt][nt] = (f32x4){0.f, 0.f, 0.f, 0.f};

    const float* xb = x + (size_t)b * T_ * D_;
    for (int kb = 0; kb < D_ / 32; kb++) {
        int kofs = kb * 32 + lhi * 8;
        bf16x8 ah[4], al[4];
#pragma unroll
        for (int mt = 0; mt < 4; mt++) {
            int t = t0 + mt * 16 + l15;
            split_frag_nt(xb + (size_t)t * D_ + kofs, ah[mt], al[mt]);
        }
#pragma unroll
        for (int nt = 0; nt < 4; nt++) {
            size_t wb = (((size_t)(w * 4 + nt) * 8 + kb) << 9) + lane * 8;  // KB=8
            bf16x8 bh = *(const bf16x8*)(Wp_hi + wb);
            bf16x8 bl = *(const bf16x8*)(Wp_lo + wb);
#pragma unroll
            for (int mt = 0; mt < 4; mt++) {
                acc[mt][nt] = MFMA16(ah[mt], bh, acc[mt][nt]);
                acc[mt][nt] = MFMA16(al[mt], bh, acc[mt][nt]);
                acc[mt][nt] = MFMA16(ah[mt], bl, acc[mt][nt]);
            }
        }
    }
#pragma unroll
    for (int nt = 0; nt < 4; nt++) {
        int n = nb + nt * 16 + l15;
        float bias = bih[n] + bhh[n];
#pragma unroll
        for (int mt = 0; mt < 4; mt++) {
#pragma unroll
            for (int r = 0; r < 4; r++) {
                int t = t0 + mt * 16 + lhi * 4 + r;
                zb[((size_t)b * T_ + t) * H_ + n] = acc[mt][nt][r] + bias;
            }
        }
    }
}

// ---------------------------------------------------------------------------
// Phase 1: per-chunk local recurrence l_t = xw_t + l_{t-1} @ W_hh^T (from 0),
// in place over zb (fp32, [b][t][h]). State fp32 via split-bf16 hi/lo LDS.
// grid C_CH, block 512.
// ---------------------------------------------------------------------------
__global__ __launch_bounds__(512) void k_phase1(const unsigned short* __restrict__ Wp_hi,
                                                const unsigned short* __restrict__ Wp_lo,
                                                float* __restrict__ zb) {
    __shared__ __attribute__((aligned(16))) unsigned short hA[16384];
    __shared__ __attribute__((aligned(16))) unsigned short lA[16384];
    int c = blockIdx.x;
    int w = threadIdx.x >> 6;
    int lane = threadIdx.x & 63;
    int l15 = lane & 15, lhi = lane >> 4;

    for (int i = threadIdx.x; i < 16384; i += 512) { hA[i] = 0; lA[i] = 0; }
    __syncthreads();

    for (int j = 0; j < S_CH; j++) {
        int t = c * S_CH + j;
        // issue this step's xw loads early; they resolve under the MFMA loop
        float xw[2][4][4];
#pragma unroll
        for (int mt = 0; mt < 2; mt++)
#pragma unroll
            for (int nt = 0; nt < 4; nt++) {
                int n = w * 64 + nt * 16 + l15;
#pragma unroll
                for (int r = 0; r < 4; r++) {
                    int b = mt * 16 + lhi * 4 + r;
                    xw[mt][nt][r] = zb[((size_t)b * T_ + t) * H_ + n];
                }
            }
        f32x4 acc[2][4];
#pragma unroll
        for (int mt = 0; mt < 2; mt++)
#pragma unroll
            for (int nt = 0; nt < 4; nt++) acc[mt][nt] = (f32x4){0.f, 0.f, 0.f, 0.f};
        if (j > 0) {
            for (int kb = 0; kb < 16; kb++) {
                bf16x8 ah0 = *(const bf16x8*)&hA[(kb << 9) + lane * 8];
                bf16x8 ah1 = *(const bf16x8*)&hA[((16 + kb) << 9) + lane * 8];
                bf16x8 al0 = *(const bf16x8*)&lA[(kb << 9) + lane * 8];
                bf16x8 al1 = *(const bf16x8*)&lA[((16 + kb) << 9) + lane * 8];
#pragma unroll
                for (int nt = 0; nt < 4; nt++) {
                    size_t wb = (((size_t)(w * 4 + nt) * 16 + kb) << 9) + lane * 8;
                    bf16x8 bh = *(const bf16x8*)(Wp_hi + wb);
                    bf16x8 bl = *(const bf16x8*)(Wp_lo + wb);
                    acc[0][nt] = MFMA16(ah0, bh, acc[0][nt]);
                    acc[0][nt] = MFMA16(al0, bh, acc[0][nt]);
                    acc[0][nt] = MFMA16(ah0, bl, acc[0][nt]);
                    acc[1][nt] = MFMA16(ah1, bh, acc[1][nt]);
                    acc[1][nt] = MFMA16(al1, bh, acc[1][nt]);
                    acc[1][nt] = MFMA16(ah1, bl, acc[1][nt]);
                }
            }
        }
        __syncthreads();  // all waves done reading previous h before overwrite
#pragma unroll
        for (int mt = 0; mt < 2; mt++) {
#pragma unroll
            for (int nt = 0; nt < 4; nt++) {
                int n = w * 64 + nt * 16 + l15;
#pragma unroll
                for (int r = 0; r < 4; r++) {
                    int b = mt * 16 + lhi * 4 + r;
                    float v = acc[mt][nt][r] + xw[mt][nt][r];
                    zb[((size_t)b * T_ + t) * H_ + n] = v;  // l_t (fp32)
                    unsigned short hi = f2bf_rne(v);
                    int o = hfrag_off(b, n);
                    hA[o] = hi;
                    lA[o] = f2bf_rne(v - bf2f(hi));
                }
            }
        }
        __syncthreads();
    }
}

// ---------------------------------------------------------------------------
// Carry broadcast as ONE GEMM (replaces the serial phase 3):
//   zb[b][c*8+j][n] += Hin[c][b][:] @ (W^(j+1))^T
// A = Hin (8192 x 512 fp32, split on the fly), B = Pp (stacked W^1..W^8,
// 4096 x 512 packed bf16 hi/lo). M=8192, N=4096, K=512.
// BM=128, BN=256, block 512 (8 waves as 2M x 4N), no LDS, no barriers.
// Grid 1024 with XCD swizzle: each XCD owns 2 N-panels (1 MB of B hot in L2).
// ---------------------------------------------------------------------------
__global__ __launch_bounds__(512) void k_carry(const float* __restrict__ Hin,
                                               const unsigned short* __restrict__ Pp_hi,
                                               const unsigned short* __restrict__ Pp_lo,
                                               float* __restrict__ zb) {
    int bid = blockIdx.x;
    int swz = (bid & 7) * 128 + (bid >> 3);   // XCD k -> swz in [k*128,(k+1)*128)
    int npanel = swz >> 6;                    // 0..15 (N-panel of 256 cols)
    int mtile  = swz & 63;                    // 0..63 (M-tile of 128 rows)
    int w = threadIdx.x >> 6, lane = threadIdx.x & 63;
    int l15 = lane & 15, lhi = lane >> 4;
    int wm = w >> 2, wn = w & 3;
    int m0 = mtile * 128 + wm * 64;
    int n16base = npanel * 16 + wn * 4;       // global 16-col fragment index

    f32x4 acc[4][4];
#pragma unroll
    for (int mt = 0; mt < 4; mt++)
#pragma unroll
        for (int nt = 0; nt < 4; nt++) acc[mt][nt] = (f32x4){0.f, 0.f, 0.f, 0.f};

    for (int kb = 0; kb < 16; kb++) {
        int kofs = kb * 32 + lhi * 8;
        bf16x8 ah[4], al[4];
#pragma unroll
        for (int mt = 0; mt < 4; mt++)
            split_frag(Hin + (size_t)(m0 + mt * 16 + l15) * H_ + kofs, ah[mt], al[mt]);
#pragma unroll
        for (int nt = 0; nt < 4; nt++) {
            size_t wb = (((size_t)(n16base + nt) * 16 + kb) << 9) + lane * 8;
            bf16x8 bh = *(const bf16x8*)(Pp_hi + wb);
            bf16x8 bl = *(const bf16x8*)(Pp_lo + wb);
#pragma unroll
            for (int mt = 0; mt < 4; mt++) {
                acc[mt][nt] = MFMA16(ah[mt], bh, acc[mt][nt]);
                acc[mt][nt] = MFMA16(al[mt], bh, acc[mt][nt]);
                acc[mt][nt] = MFMA16(ah[mt], bl, acc[mt][nt]);
            }
        }
    }
    // epilogue: z_t = l_t + acc, scattered into zb[b][t][n]
#pragma unroll
    for (int nt = 0; nt < 4; nt++) {
        int col = (n16base + nt) * 16 + l15;  // 0..4095
        int j = col >> 9, n = col & 511;
#pragma unroll
        for (int mt = 0; mt < 4; mt++) {
#pragma unroll
            for (int r = 0; r < 4; r++) {
                int m = m0 + mt * 16 + lhi * 4 + r;   // (c,b) row
                int c = m >> 5, b = m & 31;
                size_t zi = ((size_t)b * T_ + (c * S_CH + j)) * H_ + n;
                zb[zi] += acc[mt][nt][r];
            }
        }
    }
}

// ---------------------------------------------------------------------------
// K5: logits = z @ W_lin^T + b_lin, fused softmax over O=256, fp32 out.
// grid (B*T/64), block 256 (4 waves; wave w owns rows 16w..16w+15, all cols).
// ---------------------------------------------------------------------------
__global__ __launch_bounds__(256) void k_logits(const float* __restrict__ zq,
                                                const unsigned short* __restrict__ Wp_hi,
                                                const float* __restrict__ blin,
                                                float* __restrict__ out) {
    size_t row0 = (size_t)blockIdx.x * 64;
    int w = threadIdx.x >> 6, lane = threadIdx.x & 63;
    int l15 = lane & 15, lhi = lane >> 4;

    f32x4 acc[16];
#pragma unroll
    for (int nt = 0; nt < 16; nt++) acc[nt] = (f32x4){0.f, 0.f, 0.f, 0.f};

    const float* arow = zq + (row0 + (size_t)w * 16 + l15) * H_;
    for (int kb = 0; kb < 16; kb++) {
        int kofs = kb * 32 + lhi * 8;
        bf16x8 ah, al;
        split_frag_nt(arow + kofs, ah, al);
#pragma unroll
        for (int nt = 0; nt < 16; nt++) {
            size_t wb = (((size_t)nt * 16 + kb) << 9) + lane * 8;  // n16 = nt, KB=16
            bf16x8 bh = *(const bf16x8*)(Wp_hi + wb);
            acc[nt] = MFMA16(ah, bh, acc[nt]);
            acc[nt] = MFMA16(al, bh, acc[nt]);
        }
    }
#pragma unroll
    for (int nt = 0; nt < 16; nt++) {
        float bb = blin[nt * 16 + l15];
#pragma unroll
        for (int r = 0; r < 4; r++) acc[nt][r] += bb;
    }
    float rmax[4], rinv[4];
#pragma unroll
    for (int r = 0; r < 4; r++) {
        float mx = -INFINITY;
#pragma unroll
        for (int nt = 0; nt < 16; nt++) mx = fmaxf(mx, acc[nt][r]);
        for (int s = 1; s < 16; s <<= 1) mx = fmaxf(mx, __shfl_xor(mx, s));
        float sum = 0.f;
#pragma unroll
        for (int nt = 0; nt < 16; nt++) sum += __expf(acc[nt][r] - mx);
        for (int s = 1; s < 16; s <<= 1) sum += __shfl_xor(sum, s);
        rmax[r] = mx;
        rinv[r] = 1.f / sum;
    }
#pragma unroll
    for (int nt = 0; nt < 16; nt++) {
#pragma unroll
        for (int r = 0; r < 4; r++) {
            float e = __expf(acc[nt][r] - rmax[r]) * rinv[r];
            size_t row = row0 + (size_t)w * 16 + lhi * 4 + r;
            out[row * O_ + nt * 16 + l15] = e;
        }
    }
}

// ---------------------------------------------------------------------------
extern "C" void kernel_launch(void* const* d_in, const int* in_sizes, int n_in,
                              void* d_out, int out_size, void* d_ws, size_t ws_size,
                              hipStream_t stream) {
    const float* x    = (const float*)d_in[0];
    const float* h0   = (const float*)d_in[1];
    const float* Wih  = (const float*)d_in[2];
    const float* Whh  = (const float*)d_in[3];
    const float* bih  = (const float*)d_in[4];
    const float* bhh  = (const float*)d_in[5];
    const float* Wlin = (const float*)d_in[6];
    const float* blin = (const float*)d_in[7];

    float* out  = (float*)d_out;
    float* zout = out + (size_t)B_ * T_ * O_;  // z region of d_out (fp32, in-place)

    // ws layout (~16.5 MB): M[0..13] fp32 power matrices | small packed weights.
    // Large packed power sets (Pp, Qp: 16 MB) + Va/Vb (32 MB) live in the
    // softmax-out region of d_out, dead until k_logits (the final launch).
    float* ws = (float*)d_ws;
    float* M[14];   // W^2,W^3,W^4,W^5,W^6,W^7,W^8,W^16,...,W^1024
    for (int i = 0; i < 14; i++) M[i] = ws + (size_t)i * H_ * H_;
    unsigned short* Whh_hi = (unsigned short*)(ws + (size_t)14 * H_ * H_);
    unsigned short* Whh_lo = Whh_hi + (size_t)H_ * H_;
    unsigned short* Wih_hi = Whh_lo + (size_t)H_ * H_;
    unsigned short* Wih_lo = Wih_hi + (size_t)H_ * D_;
    unsigned short* Wlin_hi = Wih_lo + (size_t)H_ * D_;
    unsigned short* Wlin_lo = Wlin_hi + (size_t)O_ * H_;
    (void)Wlin_lo;

    float* Va = out;                            // [0,16MB)
    float* Vb = out + (size_t)C_CH * B_ * H_;   // [16,32MB)
    unsigned short* Pp_hi = (unsigned short*)((char*)d_out + (size_t)32 * 1024 * 1024);
    unsigned short* Pp_lo = Pp_hi + (size_t)8 * H_ * H_;   // [36,40MB)
    unsigned short* Qp_hi = Pp_lo + (size_t)8 * H_ * H_;   // [40,44MB)
    unsigned short* Qp_lo = Qp_hi + (size_t)8 * H_ * H_;   // [44,48MB) < 64MB ✓

    // Pack direct-use weights (frag-major, bf16 hi/lo)
    k_pack<<<dim3((H_ * H_) / 256), 256, 0, stream>>>(Whh, Whh_hi, Whh_lo, H_ * H_, 9);
    k_pack<<<dim3((H_ * D_) / 256), 256, 0, stream>>>(Wih, Wih_hi, Wih_lo, H_ * D_, 8);
    k_pack<<<dim3((O_ * H_) / 256), 256, 0, stream>>>(Wlin, Wlin_hi, Wlin_lo, O_ * H_, 9);

    // fp32 power chain: W^2..W^8, then W^16..W^1024 by squaring
    dim3 g16(16, 16);
    k_mul<<<g16, 256, 0, stream>>>(Whh, Whh, M[0]);   // W^2
    k_mul<<<g16, 256, 0, stream>>>(Whh, M[0], M[1]);  // W^3
    k_mul<<<g16, 256, 0, stream>>>(M[0], M[0], M[2]); // W^4
    k_mul<<<g16, 256, 0, stream>>>(Whh, M[2], M[3]);  // W^5
    k_mul<<<g16, 256, 0, stream>>>(M[0], M[2], M[4]); // W^6
    k_mul<<<g16, 256, 0, stream>>>(M[1], M[2], M[5]); // W^7
    k_mul<<<g16, 256, 0, stream>>>(M[2], M[2], M[6]); // W^8
    for (int i = 7; i < 14; i++)                      // W^16..W^1024
        k_mul<<<g16, 256, 0, stream>>>(M[i - 1], M[i - 1], M[i]);

    // Pack stacked P = [W^1..W^8] for k_carry (slice j-1 = W^j)
    k_pack<<<dim3((H_ * H_) / 256), 256, 0, stream>>>(Whh, Pp_hi, Pp_lo, H_ * H_, 9);
    for (int j = 2; j <= 8; j++)
        k_pack<<<dim3((H_ * H_) / 256), 256, 0, stream>>>(
            M[j - 2], Pp_hi + (size_t)(j - 1) * H_ * H_, Pp_lo + (size_t)(j - 1) * H_ * H_,
            H_ * H_, 9);
    // Pack scan-level matrices W^(8*2^l), l=0..7 (= M[6..13])
    for (int l = 0; l < 8; l++)
        k_pack<<<dim3((H_ * H_) / 256), 256, 0, stream>>>(
            M[6 + l], Qp_hi + (size_t)l * H_ * H_, Qp_lo + (size_t)l * H_ * H_, H_ * H_, 9);

    // xw into z region
    k_xw<<<dim3(T_ / 64, B_), 512, 0, stream>>>(x, Wih_hi, Wih_lo, bih, bhh, zout);

    // local chunk scans (256 chunks of 8 steps)
    k_phase1<<<dim3(C_CH), 512, 0, stream>>>(Whh_hi, Whh_lo, zout);

    // chunk-carry Kogge-Stone scan (split-bf16 MFMA): level l shift 2^l
    k_seed<<<dim3((C_CH * B_ * H_) / 256), 256, 0, stream>>>(h0, zout, Va);
    {
        float* vin = Va;
        float* vout = Vb;
        int s = 1;
        for (int l = 0; l < 8; l++) {
            k_scan2<<<dim3(C_CH), 512, 0, stream>>>(
                vin, Qp_hi + (size_t)l * H_ * H_, Qp_lo + (size_t)l * H_ * H_, vout, s);
            float* tmp = vin; vin = vout; vout = tmp;
            s <<= 1;
        }
        // 8 swaps -> final result back in Va
    }

    // carry broadcast as one big GEMM + in-place add into zb
    k_carry<<<dim3(1024), 512, 0, stream>>>(Va, Pp_hi, Pp_lo, zout);

    // logits + softmax
    k_logits<<<dim3((B_ * T_) / 64), 256, 0, stream>>>(zout, Wlin_hi, blin, out);
}

// Round 5
// 1352.918 us; speedup vs baseline: 2.1993x; 1.1848x over previous
//
#include <hip/hip_runtime.h>
#include <math.h>

// Problem constants
#define B_ 32
#define T_ 2048
#define D_ 256
#define H_ 512
#define O_ 256
#define S_CH 8               // chunk length
#define C_CH 256             // number of chunks = T/S: 1 block per CU

typedef short bf16x8 __attribute__((ext_vector_type(8)));  // 8 bf16 (4 VGPRs) MFMA frag
typedef float f32x4  __attribute__((ext_vector_type(4)));

#define NTL(p)     __builtin_nontemporal_load(p)

__device__ __forceinline__ unsigned short f2bf_rne(float x) {
    unsigned int u = __builtin_bit_cast(unsigned int, x);
    unsigned int r = (u + 0x7fffu + ((u >> 16) & 1u)) >> 16;
    return (unsigned short)r;
}
__device__ __forceinline__ float bf2f(unsigned short h) {
    unsigned int u = ((unsigned int)h) << 16;
    return __builtin_bit_cast(float, u);
}

#define MFMA16(a, b, c) __builtin_amdgcn_mfma_f32_16x16x32_bf16((a), (b), (c), 0, 0, 0)

// Build split-bf16 A-fragments (hi+lo) from 8 consecutive fp32 values.
__device__ __forceinline__ void split_frag(const float* p, bf16x8& hi, bf16x8& lo) {
    f32x4 a = *(const f32x4*)p;
    f32x4 b = *(const f32x4*)(p + 4);
#pragma unroll
    for (int i = 0; i < 4; i++) {
        unsigned short h = f2bf_rne(a[i]);
        hi[i] = (short)h; lo[i] = (short)f2bf_rne(a[i] - bf2f(h));
        unsigned short h2 = f2bf_rne(b[i]);
        hi[4 + i] = (short)h2; lo[4 + i] = (short)f2bf_rne(b[i] - bf2f(h2));
    }
}
// Same, but non-temporal loads (pure read-once streams: x, zq).
__device__ __forceinline__ void split_frag_nt(const float* p, bf16x8& hi, bf16x8& lo) {
    f32x4 a = NTL((const f32x4*)p);
    f32x4 b = NTL((const f32x4*)(p + 4));
#pragma unroll
    for (int i = 0; i < 4; i++) {
        unsigned short h = f2bf_rne(a[i]);
        hi[i] = (short)h; lo[i] = (short)f2bf_rne(a[i] - bf2f(h));
        unsigned short h2 = f2bf_rne(b[i]);
        hi[4 + i] = (short)h2; lo[4 + i] = (short)f2bf_rne(b[i] - bf2f(h2));
    }
}

// Fragment-major packed offset for a B-matrix element (n, k), KB = K/32.
__device__ __forceinline__ size_t wpack_off(int n, int k, int KB) {
    int n16 = n >> 4, l15 = n & 15;
    int kb = k >> 5, lhi = (k >> 3) & 3, j = k & 7;
    return (((size_t)(n16 * KB + kb) * 4 + lhi) * 16 + l15) * 8 + j;
}

// Same layout for the LDS-resident h state (m over 32 batches, n over 512).
__device__ __forceinline__ int hfrag_off(int m, int n) {
    int m16 = m >> 4, l15m = m & 15;
    int kb = n >> 5, lhi = (n >> 3) & 3, j = n & 7;
    return (((m16 * 16 + kb) * 4 + lhi) * 16 + l15m) * 8 + j;
}

// ---------------------------------------------------------------------------
// Pack fp32 matrix into frag-major bf16 hi/lo. kshift: 9 (K=512) or 8 (K=256).
// ---------------------------------------------------------------------------
__global__ void k_pack(const float* __restrict__ in, unsigned short* __restrict__ hi,
                       unsigned short* __restrict__ lo, int total, int kshift) {
    int i = blockIdx.x * 256 + threadIdx.x;
    if (i < total) {
        int n = i >> kshift;
        int k = i & ((1 << kshift) - 1);
        float v = in[i];
        unsigned short h = f2bf_rne(v);
        size_t o = wpack_off(n, k, 1 << (kshift - 5));
        hi[o] = h;
        lo[o] = f2bf_rne(v - bf2f(h));
    }
}

// ---------------------------------------------------------------------------
// fp32 matmul: Out = A * Bm  (512x512 row-major), grid (16,16), block 256.
// Fused epilogue: optionally write the result packed (frag-major bf16 hi/lo)
// to up to two destinations (d1, d2) — replaces separate k_pack launches.
// ---------------------------------------------------------------------------
__global__ __launch_bounds__(256) void k_mul(const float* __restrict__ A,
                                             const float* __restrict__ Bm,
                                             float* __restrict__ Out,
                                             unsigned short* __restrict__ d1h,
                                             unsigned short* __restrict__ d1l,
                                             unsigned short* __restrict__ d2h,
                                             unsigned short* __restrict__ d2l) {
    __shared__ float As[32][33];
    __shared__ float Bs[32][33];
    int tx = threadIdx.x & 15, ty = threadIdx.x >> 4;
    int j0 = blockIdx.x * 32, i0 = blockIdx.y * 32;
    float a00 = 0.f, a01 = 0.f, a10 = 0.f, a11 = 0.f;
    int r  = threadIdx.x >> 3;
    int c4 = (threadIdx.x & 7) * 4;
    for (int kb = 0; kb < H_ / 32; kb++) {
        f32x4 va = *(const f32x4*)(A + (size_t)(i0 + r) * H_ + kb * 32 + c4);
        f32x4 vb = *(const f32x4*)(Bm + (size_t)(kb * 32 + r) * H_ + j0 + c4);
        __syncthreads();
        As[r][c4 + 0] = va[0]; As[r][c4 + 1] = va[1]; As[r][c4 + 2] = va[2]; As[r][c4 + 3] = va[3];
        Bs[r][c4 + 0] = vb[0]; Bs[r][c4 + 1] = vb[1]; Bs[r][c4 + 2] = vb[2]; Bs[r][c4 + 3] = vb[3];
        __syncthreads();
#pragma unroll
        for (int k = 0; k < 32; k++) {
            float b0 = Bs[k][tx * 2], b1 = Bs[k][tx * 2 + 1];
            float a0 = As[ty * 2][k], a1 = As[ty * 2 + 1][k];
            a00 += a0 * b0; a01 += a0 * b1; a10 += a1 * b0; a11 += a1 * b1;
        }
    }
    float vals[4] = {a00, a01, a10, a11};
#pragma unroll
    for (int q = 0; q < 4; q++) {
        int n = i0 + ty * 2 + (q >> 1);
        int k = j0 + tx * 2 + (q & 1);
        Out[(size_t)n * H_ + k] = vals[q];
        unsigned short h = f2bf_rne(vals[q]);
        unsigned short l = f2bf_rne(vals[q] - bf2f(h));
        size_t o = wpack_off(n, k, 16);
        if (d1h) { d1h[o] = h; d1l[o] = l; }
        if (d2h) { d2h[o] = h; d2l[o] = l; }
    }
}

// ---------------------------------------------------------------------------
// Seed the chunk-carry scan inputs: v[0]=h0, v[c]=l_end(c-1) from zb.
// ---------------------------------------------------------------------------
__global__ void k_seed(const float* __restrict__ h0, const float* __restrict__ zb,
                       float* __restrict__ Va) {
    int i = blockIdx.x * 256 + threadIdx.x;  // over C*B*H
    int c = i >> 14;             // B*H = 16384
    int bn = i & 16383;
    int b = bn >> 9, n = bn & 511;
    Va[i] = (c == 0) ? h0[bn] : zb[((size_t)b * T_ + (c * S_CH - 1)) * H_ + n];
}

// ---------------------------------------------------------------------------
// One Kogge-Stone scan level via split-bf16 MFMA:
// Vout[c] = Vin[c] + Vin[c-s] @ (W^(S*s))^T  (c >= s), else copy.
// grid C_CH, block 1024 (16 waves; wave w owns 32-col n-slice, nt 0..1).
// ---------------------------------------------------------------------------
__global__ __launch_bounds__(1024) void k_scan2(const float* __restrict__ Vin,
                                                const unsigned short* __restrict__ Qp_hi,
                                                const unsigned short* __restrict__ Qp_lo,
                                                float* __restrict__ Vout, int s) {
    __shared__ __attribute__((aligned(16))) unsigned short hA[16384];
    __shared__ __attribute__((aligned(16))) unsigned short lA[16384];
    int c = blockIdx.x;
    int w = threadIdx.x >> 6;
    int lane = threadIdx.x & 63;
    int l15 = lane & 15, lhi = lane >> 4;

    if (c < s) {  // pure copy
        size_t base = (size_t)c * B_ * H_;
        for (int i = threadIdx.x * 4; i < B_ * H_; i += 4096) {
            f32x4 v = *(const f32x4*)(Vin + base + i);
            *(f32x4*)(Vout + base + i) = v;
        }
        return;
    }

    // stage Vin[c-s] as split-bf16 frag-major in LDS
    size_t src = (size_t)(c - s) * B_ * H_;
    for (int i = threadIdx.x; i < 16384; i += 1024) {
        float v = Vin[src + i];               // i = m*512 + n, row-major
        int m = i >> 9, n = i & 511;
        unsigned short hi = f2bf_rne(v);
        int o = hfrag_off(m, n);
        hA[o] = hi;
        lA[o] = f2bf_rne(v - bf2f(hi));
    }
    __syncthreads();

    // issue the additive Vin[c] loads early (overlap with MFMA)
    size_t dst = (size_t)c * B_ * H_;
    float ad[2][2][4];
#pragma unroll
    for (int mt = 0; mt < 2; mt++)
#pragma unroll
        for (int nt = 0; nt < 2; nt++) {
            int n = w * 32 + nt * 16 + l15;
#pragma unroll
            for (int r = 0; r < 4; r++) {
                int m = mt * 16 + lhi * 4 + r;
                ad[mt][nt][r] = Vin[dst + (size_t)m * H_ + n];
            }
        }

    f32x4 acc[2][2];
#pragma unroll
    for (int mt = 0; mt < 2; mt++)
#pragma unroll
        for (int nt = 0; nt < 2; nt++) acc[mt][nt] = (f32x4){0.f, 0.f, 0.f, 0.f};

    for (int kb = 0; kb < 16; kb++) {
        bf16x8 ah0 = *(const bf16x8*)&hA[(kb << 9) + lane * 8];
        bf16x8 ah1 = *(const bf16x8*)&hA[((16 + kb) << 9) + lane * 8];
        bf16x8 al0 = *(const bf16x8*)&lA[(kb << 9) + lane * 8];
        bf16x8 al1 = *(const bf16x8*)&lA[((16 + kb) << 9) + lane * 8];
#pragma unroll
        for (int nt = 0; nt < 2; nt++) {
            size_t wb = (((size_t)(w * 2 + nt) * 16 + kb) << 9) + lane * 8;
            bf16x8 bh = *(const bf16x8*)(Qp_hi + wb);
            bf16x8 bl = *(const bf16x8*)(Qp_lo + wb);
            acc[0][nt] = MFMA16(ah0, bh, acc[0][nt]);
            acc[0][nt] = MFMA16(al0, bh, acc[0][nt]);
            acc[0][nt] = MFMA16(ah0, bl, acc[0][nt]);
            acc[1][nt] = MFMA16(ah1, bh, acc[1][nt]);
            acc[1][nt] = MFMA16(al1, bh, acc[1][nt]);
            acc[1][nt] = MFMA16(ah1, bl, acc[1][nt]);
        }
    }
#pragma unroll
    for (int mt = 0; mt < 2; mt++)
#pragma unroll
        for (int nt = 0; nt < 2; nt++) {
            int n = w * 32 + nt * 16 + l15;
#pragma unroll
            for (int r = 0; r < 4; r++) {
                int m = mt * 16 + lhi * 4 + r;
                Vout[dst + (size_t)m * H_ + n] = acc[mt][nt][r] + ad[mt][nt][r];
            }
        }
}

// ---------------------------------------------------------------------------
// K0: zb[b][t][h] = x[b][t][:] @ W_ih^T + (b_ih + b_hh), fp32, into the z
// region of d_out. x split hi/lo on the fly; W_ih pre-split+packed; 3 MFMAs.
// grid (T/64, B), block 512 (8 waves; wave w owns n-slice 64w..64w+63)
// ---------------------------------------------------------------------------
__global__ __launch_bounds__(512) void k_xw(const float* __restrict__ x,
                                            const unsigned short* __restrict__ Wp_hi,
                                            const unsigned short* __restrict__ Wp_lo,
                                            const float* __restrict__ bih,
                                            const float* __restrict__ bhh,
                                            float* __restrict__ zb) {
    int b  = blockIdx.y;
    int t0 = blockIdx.x * 64;
    int w    = threadIdx.x >> 6;
    int lane = threadIdx.x & 63;
    int l15 = lane & 15, lhi = lane >> 4;
    int nb = w * 64;

    f32x4 acc[4][4];  // [mt][nt]
    for (int mt = 0; mt < 4; mt++)
        for (int nt = 0; nt < 4; nt++)
            acc[mt][nt] = (f32x4){0.f, 0.f, 0.f, 0.f};

    const float* xb = x + (size_t)b * T_ * D_;
    for (int kb = 0; kb < D_ / 32; kb++) {
        int kofs = kb * 32 + lhi * 8;
        bf16x8 ah[4], al[4];
#pragma unroll
        for (int mt = 0; mt < 4; mt++) {
            int t = t0 + mt * 16 + l15;
            split_frag_nt(xb + (size_t)t * D_ + kofs, ah[mt], al[mt]);
        }
#pragma unroll
        for (int nt = 0; nt < 4; nt++) {
            size_t wb = (((size_t)(w * 4 + nt) * 8 + kb) << 9) + lane * 8;  // KB=8
            bf16x8 bh = *(const bf16x8*)(Wp_hi + wb);
            bf16x8 bl = *(const bf16x8*)(Wp_lo + wb);
#pragma unroll
            for (int mt = 0; mt < 4; mt++) {
                acc[mt][nt] = MFMA16(ah[mt], bh, acc[mt][nt]);
                acc[mt][nt] = MFMA16(al[mt], bh, acc[mt][nt]);
                acc[mt][nt] = MFMA16(ah[mt], bl, acc[mt][nt]);
            }
        }
    }
#pragma unroll
    for (int nt = 0; nt < 4; nt++) {
        int n = nb + nt * 16 + l15;
        float bias = bih[n] + bhh[n];
#pragma unroll
        for (int mt = 0; mt < 4; mt++) {
#pragma unroll
            for (int r = 0; r < 4; r++) {
                int t = t0 + mt * 16 + lhi * 4 + r;
                zb[((size_t)b * T_ + t) * H_ + n] = acc[mt][nt][r] + bias;
            }
        }
    }
}

// ---------------------------------------------------------------------------
// Phase 1: per-chunk local recurrence l_t = xw_t + l_{t-1} @ W_hh^T (from 0),
// in place over zb (fp32, [b][t][h]). State fp32 via split-bf16 hi/lo LDS.
// grid C_CH, block 1024 (16 waves; wave w owns 32-col n-slice, nt 0..1).
// ---------------------------------------------------------------------------
__global__ __launch_bounds__(1024) void k_phase1(const unsigned short* __restrict__ Wp_hi,
                                                 const unsigned short* __restrict__ Wp_lo,
                                                 float* __restrict__ zb) {
    __shared__ __attribute__((aligned(16))) unsigned short hA[16384];
    __shared__ __attribute__((aligned(16))) unsigned short lA[16384];
    int c = blockIdx.x;
    int w = threadIdx.x >> 6;
    int lane = threadIdx.x & 63;
    int l15 = lane & 15, lhi = lane >> 4;
    // no LDS init needed: j==0 skips the MFMA pass entirely

    for (int j = 0; j < S_CH; j++) {
        int t = c * S_CH + j;
        // issue this step's xw loads early; they resolve under the MFMA loop
        float xw[2][2][4];
#pragma unroll
        for (int mt = 0; mt < 2; mt++)
#pragma unroll
            for (int nt = 0; nt < 2; nt++) {
                int n = w * 32 + nt * 16 + l15;
#pragma unroll
                for (int r = 0; r < 4; r++) {
                    int b = mt * 16 + lhi * 4 + r;
                    xw[mt][nt][r] = zb[((size_t)b * T_ + t) * H_ + n];
                }
            }
        f32x4 acc[2][2];
#pragma unroll
        for (int mt = 0; mt < 2; mt++)
#pragma unroll
            for (int nt = 0; nt < 2; nt++) acc[mt][nt] = (f32x4){0.f, 0.f, 0.f, 0.f};
        if (j > 0) {
            for (int kb = 0; kb < 16; kb++) {
                bf16x8 ah0 = *(const bf16x8*)&hA[(kb << 9) + lane * 8];
                bf16x8 ah1 = *(const bf16x8*)&hA[((16 + kb) << 9) + lane * 8];
                bf16x8 al0 = *(const bf16x8*)&lA[(kb << 9) + lane * 8];
                bf16x8 al1 = *(const bf16x8*)&lA[((16 + kb) << 9) + lane * 8];
#pragma unroll
                for (int nt = 0; nt < 2; nt++) {
                    size_t wb = (((size_t)(w * 2 + nt) * 16 + kb) << 9) + lane * 8;
                    bf16x8 bh = *(const bf16x8*)(Wp_hi + wb);
                    bf16x8 bl = *(const bf16x8*)(Wp_lo + wb);
                    acc[0][nt] = MFMA16(ah0, bh, acc[0][nt]);
                    acc[0][nt] = MFMA16(al0, bh, acc[0][nt]);
                    acc[0][nt] = MFMA16(ah0, bl, acc[0][nt]);
                    acc[1][nt] = MFMA16(ah1, bh, acc[1][nt]);
                    acc[1][nt] = MFMA16(al1, bh, acc[1][nt]);
                    acc[1][nt] = MFMA16(ah1, bl, acc[1][nt]);
                }
            }
        }
        __syncthreads();  // all waves done reading previous h before overwrite
#pragma unroll
        for (int mt = 0; mt < 2; mt++) {
#pragma unroll
            for (int nt = 0; nt < 2; nt++) {
                int n = w * 32 + nt * 16 + l15;
#pragma unroll
                for (int r = 0; r < 4; r++) {
                    int b = mt * 16 + lhi * 4 + r;
                    float v = acc[mt][nt][r] + xw[mt][nt][r];
                    zb[((size_t)b * T_ + t) * H_ + n] = v;  // l_t (fp32)
                    unsigned short hi = f2bf_rne(v);
                    int o = hfrag_off(b, n);
                    hA[o] = hi;
                    lA[o] = f2bf_rne(v - bf2f(hi));
                }
            }
        }
        __syncthreads();
    }
}

// ---------------------------------------------------------------------------
// Carry broadcast as ONE GEMM (replaces the serial phase 3):
//   zb[b][c*8+j][n] += Hin[c][b][:] @ (W^(j+1))^T
// A = Hin (8192 x 512 fp32, split on the fly), B = Pp (stacked W^1..W^8,
// 4096 x 512 packed bf16 hi/lo). M=8192, N=4096, K=512.
// BM=128, BN=256, block 512 (8 waves as 2M x 4N), no LDS, no barriers.
// Grid 1024 with XCD swizzle: each XCD owns 2 N-panels (1 MB of B hot in L2).
// ---------------------------------------------------------------------------
__global__ __launch_bounds__(512) void k_carry(const float* __restrict__ Hin,
                                               const unsigned short* __restrict__ Pp_hi,
                                               const unsigned short* __restrict__ Pp_lo,
                                               float* __restrict__ zb) {
    int bid = blockIdx.x;
    int swz = (bid & 7) * 128 + (bid >> 3);   // XCD k -> swz in [k*128,(k+1)*128)
    int npanel = swz >> 6;                    // 0..15 (N-panel of 256 cols)
    int mtile  = swz & 63;                    // 0..63 (M-tile of 128 rows)
    int w = threadIdx.x >> 6, lane = threadIdx.x & 63;
    int l15 = lane & 15, lhi = lane >> 4;
    int wm = w >> 2, wn = w & 3;
    int m0 = mtile * 128 + wm * 64;
    int n16base = npanel * 16 + wn * 4;       // global 16-col fragment index

    f32x4 acc[4][4];
#pragma unroll
    for (int mt = 0; mt < 4; mt++)
#pragma unroll
        for (int nt = 0; nt < 4; nt++) acc[mt][nt] = (f32x4){0.f, 0.f, 0.f, 0.f};

    for (int kb = 0; kb < 16; kb++) {
        int kofs = kb * 32 + lhi * 8;
        bf16x8 ah[4], al[4];
#pragma unroll
        for (int mt = 0; mt < 4; mt++)
            split_frag(Hin + (size_t)(m0 + mt * 16 + l15) * H_ + kofs, ah[mt], al[mt]);
#pragma unroll
        for (int nt = 0; nt < 4; nt++) {
            size_t wb = (((size_t)(n16base + nt) * 16 + kb) << 9) + lane * 8;
            bf16x8 bh = *(const bf16x8*)(Pp_hi + wb);
            bf16x8 bl = *(const bf16x8*)(Pp_lo + wb);
#pragma unroll
            for (int mt = 0; mt < 4; mt++) {
                acc[mt][nt] = MFMA16(ah[mt], bh, acc[mt][nt]);
                acc[mt][nt] = MFMA16(al[mt], bh, acc[mt][nt]);
                acc[mt][nt] = MFMA16(ah[mt], bl, acc[mt][nt]);
            }
        }
    }
    // epilogue: z_t = l_t + acc, scattered into zb[b][t][n]
#pragma unroll
    for (int nt = 0; nt < 4; nt++) {
        int col = (n16base + nt) * 16 + l15;  // 0..4095
        int j = col >> 9, n = col & 511;
#pragma unroll
        for (int mt = 0; mt < 4; mt++) {
#pragma unroll
            for (int r = 0; r < 4; r++) {
                int m = m0 + mt * 16 + lhi * 4 + r;   // (c,b) row
                int c = m >> 5, b = m & 31;
                size_t zi = ((size_t)b * T_ + (c * S_CH + j)) * H_ + n;
                zb[zi] += acc[mt][nt][r];
            }
        }
    }
}

// ---------------------------------------------------------------------------
// K5: logits = z @ W_lin^T + b_lin, fused softmax over O=256, fp32 out.
// grid (B*T/64), block 256 (4 waves; wave w owns rows 16w..16w+15, all cols).
// ---------------------------------------------------------------------------
__global__ __launch_bounds__(256) void k_logits(const float* __restrict__ zq,
                                                const unsigned short* __restrict__ Wp_hi,
                                                const float* __restrict__ blin,
                                                float* __restrict__ out) {
    size_t row0 = (size_t)blockIdx.x * 64;
    int w = threadIdx.x >> 6, lane = threadIdx.x & 63;
    int l15 = lane & 15, lhi = lane >> 4;

    f32x4 acc[16];
#pragma unroll
    for (int nt = 0; nt < 16; nt++) acc[nt] = (f32x4){0.f, 0.f, 0.f, 0.f};

    const float* arow = zq + (row0 + (size_t)w * 16 + l15) * H_;
    for (int kb = 0; kb < 16; kb++) {
        int kofs = kb * 32 + lhi * 8;
        bf16x8 ah, al;
        split_frag_nt(arow + kofs, ah, al);
#pragma unroll
        for (int nt = 0; nt < 16; nt++) {
            size_t wb = (((size_t)nt * 16 + kb) << 9) + lane * 8;  // n16 = nt, KB=16
            bf16x8 bh = *(const bf16x8*)(Wp_hi + wb);
            acc[nt] = MFMA16(ah, bh, acc[nt]);
            acc[nt] = MFMA16(al, bh, acc[nt]);
        }
    }
#pragma unroll
    for (int nt = 0; nt < 16; nt++) {
        float bb = blin[nt * 16 + l15];
#pragma unroll
        for (int r = 0; r < 4; r++) acc[nt][r] += bb;
    }
    float rmax[4], rinv[4];
#pragma unroll
    for (int r = 0; r < 4; r++) {
        float mx = -INFINITY;
#pragma unroll
        for (int nt = 0; nt < 16; nt++) mx = fmaxf(mx, acc[nt][r]);
        for (int s = 1; s < 16; s <<= 1) mx = fmaxf(mx, __shfl_xor(mx, s));
        float sum = 0.f;
#pragma unroll
        for (int nt = 0; nt < 16; nt++) sum += __expf(acc[nt][r] - mx);
        for (int s = 1; s < 16; s <<= 1) sum += __shfl_xor(sum, s);
        rmax[r] = mx;
        rinv[r] = 1.f / sum;
    }
#pragma unroll
    for (int nt = 0; nt < 16; nt++) {
#pragma unroll
        for (int r = 0; r < 4; r++) {
            float e = __expf(acc[nt][r] - rmax[r]) * rinv[r];
            size_t row = row0 + (size_t)w * 16 + lhi * 4 + r;
            out[row * O_ + nt * 16 + l15] = e;
        }
    }
}

// ---------------------------------------------------------------------------
extern "C" void kernel_launch(void* const* d_in, const int* in_sizes, int n_in,
                              void* d_out, int out_size, void* d_ws, size_t ws_size,
                              hipStream_t stream) {
    const float* x    = (const float*)d_in[0];
    const float* h0   = (const float*)d_in[1];
    const float* Wih  = (const float*)d_in[2];
    const float* Whh  = (const float*)d_in[3];
    const float* bih  = (const float*)d_in[4];
    const float* bhh  = (const float*)d_in[5];
    const float* Wlin = (const float*)d_in[6];
    const float* blin = (const float*)d_in[7];

    float* out  = (float*)d_out;
    float* zout = out + (size_t)B_ * T_ * O_;  // z region of d_out (fp32, in-place)

    // ws layout (~16.5 MB): M[0..13] fp32 power matrices | small packed weights.
    // Large packed power sets (Pp, Qp: 16 MB) + Va/Vb (32 MB) live in the
    // softmax-out region of d_out, dead until k_logits (the final launch).
    float* ws = (float*)d_ws;
    float* M[14];   // W^2,W^3,W^4,W^5,W^6,W^7,W^8,W^16,...,W^1024
    for (int i = 0; i < 14; i++) M[i] = ws + (size_t)i * H_ * H_;
    unsigned short* Whh_hi = (unsigned short*)(ws + (size_t)14 * H_ * H_);
    unsigned short* Whh_lo = Whh_hi + (size_t)H_ * H_;
    unsigned short* Wih_hi = Whh_lo + (size_t)H_ * H_;
    unsigned short* Wih_lo = Wih_hi + (size_t)H_ * D_;
    unsigned short* Wlin_hi = Wih_lo + (size_t)H_ * D_;
    unsigned short* Wlin_lo = Wlin_hi + (size_t)O_ * H_;
    (void)Wlin_lo;

    float* Va = out;                            // [0,16MB)
    float* Vb = out + (size_t)C_CH * B_ * H_;   // [16,32MB)
    unsigned short* Pp_hi = (unsigned short*)((char*)d_out + (size_t)32 * 1024 * 1024);
    unsigned short* Pp_lo = Pp_hi + (size_t)8 * H_ * H_;   // [36,40MB)
    unsigned short* Qp_hi = Pp_lo + (size_t)8 * H_ * H_;   // [40,44MB)
    unsigned short* Qp_lo = Qp_hi + (size_t)8 * H_ * H_;   // [44,48MB) < 64MB ✓

    // Pack direct-use weights (frag-major, bf16 hi/lo)
    k_pack<<<dim3((H_ * H_) / 256), 256, 0, stream>>>(Whh, Whh_hi, Whh_lo, H_ * H_, 9);
    k_pack<<<dim3((H_ * H_) / 256), 256, 0, stream>>>(Whh, Pp_hi, Pp_lo, H_ * H_, 9);  // Pp slice 0 = W^1
    k_pack<<<dim3((H_ * D_) / 256), 256, 0, stream>>>(Wih, Wih_hi, Wih_lo, H_ * D_, 8);
    k_pack<<<dim3((O_ * H_) / 256), 256, 0, stream>>>(Wlin, Wlin_hi, Wlin_lo, O_ * H_, 9);

    // fp32 power chain with fused packing: W^2..W^8 -> Pp slices 1..7,
    // W^8..W^1024 -> Qp slices 0..7
    dim3 g16(16, 16);
    size_t HH = (size_t)H_ * H_;
    unsigned short* nul = nullptr;
#define PPH(s) (Pp_hi + (size_t)(s) * HH)
#define PPL(s) (Pp_lo + (size_t)(s) * HH)
#define QPH(s) (Qp_hi + (size_t)(s) * HH)
#define QPL(s) (Qp_lo + (size_t)(s) * HH)
    k_mul<<<g16, 256, 0, stream>>>(Whh, Whh, M[0], PPH(1), PPL(1), nul, nul);   // W^2
    k_mul<<<g16, 256, 0, stream>>>(Whh, M[0], M[1], PPH(2), PPL(2), nul, nul);  // W^3
    k_mul<<<g16, 256, 0, stream>>>(M[0], M[0], M[2], PPH(3), PPL(3), nul, nul); // W^4
    k_mul<<<g16, 256, 0, stream>>>(Whh, M[2], M[3], PPH(4), PPL(4), nul, nul);  // W^5
    k_mul<<<g16, 256, 0, stream>>>(M[0], M[2], M[4], PPH(5), PPL(5), nul, nul); // W^6
    k_mul<<<g16, 256, 0, stream>>>(M[1], M[2], M[5], PPH(6), PPL(6), nul, nul); // W^7
    k_mul<<<g16, 256, 0, stream>>>(M[2], M[2], M[6], PPH(7), PPL(7), QPH(0), QPL(0)); // W^8
    for (int i = 7; i < 14; i++)                      // W^16..W^1024 -> Qp 1..7
        k_mul<<<g16, 256, 0, stream>>>(M[i - 1], M[i - 1], M[i],
                                       QPH(i - 6), QPL(i - 6), nul, nul);
#undef PPH
#undef PPL
#undef QPH
#undef QPL

    // xw into z region
    k_xw<<<dim3(T_ / 64, B_), 512, 0, stream>>>(x, Wih_hi, Wih_lo, bih, bhh, zout);

    // local chunk scans (256 chunks of 8 steps), 16 waves/block
    k_phase1<<<dim3(C_CH), 1024, 0, stream>>>(Whh_hi, Whh_lo, zout);

    // chunk-carry Kogge-Stone scan (split-bf16 MFMA): level l shift 2^l
    k_seed<<<dim3((C_CH * B_ * H_) / 256), 256, 0, stream>>>(h0, zout, Va);
    {
        float* vin = Va;
        float* vout = Vb;
        int s = 1;
        for (int l = 0; l < 8; l++) {
            k_scan2<<<dim3(C_CH), 1024, 0, stream>>>(
                vin, Qp_hi + (size_t)l * HH, Qp_lo + (size_t)l * HH, vout, s);
            float* tmp = vin; vin = vout; vout = tmp;
            s <<= 1;
        }
        // 8 swaps -> final result back in Va
    }

    // carry broadcast as one big GEMM + in-place add into zb
    k_carry<<<dim3(1024), 512, 0, stream>>>(Va, Pp_hi, Pp_lo, zout);

    // logits + softmax
    k_logits<<<dim3((B_ * T_) / 64), 256, 0, stream>>>(zout, Wlin_hi, blin, out);
}